// Round 5
// baseline (460.470 us; speedup 1.0000x reference)
//
#include <hip/hip_runtime.h>
#include <hip/hip_bf16.h>
#include <cmath>

#define NN 30000
#define KK 25
#define IN_F 64
#define FEAT 32
#define HH 128
#define OUTF 64
#define EE 480000
#define NPAGE 469              // dst pages of 64 nodes
#define NB (8 * NPAGE)         // sort buckets
#define NEPAD (3752 * 128)     // 480256 padded sorted-edge slots

typedef __attribute__((ext_vector_type(8))) __bf16 bf16x8;
typedef __attribute__((ext_vector_type(16))) float f32x16;

__device__ inline float u2f(unsigned u) { return __builtin_bit_cast(float, u); }
__device__ inline unsigned short f2b(float f) {
    __bf16 h = (__bf16)f;
    return __builtin_bit_cast(unsigned short, h);
}
__device__ inline float blo(unsigned u) { return u2f(u << 16); }
__device__ inline float bhi(unsigned u) { return u2f(u & 0xffff0000u); }

// ---------------- K2: d1,d2 = dist MLPs (N*K each) ----------------
__global__ void k_dmlp(const float* __restrict__ dmax,
                       const float* __restrict__ w1a, const float* __restrict__ b1a,
                       const float* __restrict__ w2a, const float* __restrict__ b2a,
                       const float* __restrict__ w1b, const float* __restrict__ b1b,
                       const float* __restrict__ w2b, const float* __restrict__ b2b,
                       float* __restrict__ d1, float* __restrict__ d2) {
    int i = blockIdx.x * 256 + threadIdx.x;
    if (i >= NN * KK) return;
    float dm = dmax[i];
    float a1 = 0.f, a2 = 0.f;
#pragma unroll 8
    for (int h = 0; h < HH; ++h) {
        float t1 = fmaxf(fmaf(dm, w1a[h], b1a[h]), 0.f);
        a1 = fmaf(t1, w2a[h], a1);
        float t2 = fmaxf(fmaf(dm, w1b[h], b1b[h]), 0.f);
        a2 = fmaf(t2, w2b[h], a2);
    }
    d1[i] = a1 + b2a[0];
    d2[i] = a2 + b2b[0];
}

// ---------------- K0: weight prep (fused w_pre@l1wh, ff_w2 transpose) ----------------
__global__ void k_wprep(const float* __restrict__ w_pre, const float* __restrict__ b_pre,
                        const float* __restrict__ l1wh, const float* __restrict__ l1bh,
                        const float* __restrict__ ffw2,
                        float* __restrict__ wfuse, float* __restrict__ bfuse,
                        unsigned short* __restrict__ wt) {
    int gid = blockIdx.x * 256 + threadIdx.x;
    if (gid < 128 * 128) {
        int j = gid >> 7, h = gid & 127;
        int half = j >> 6, jj = j & 63;
        const float* wrow = w_pre + jj * FEAT;
        const float* wh = l1wh + half * FEAT * HH + h;
        float acc = 0.f;
#pragma unroll
        for (int c = 0; c < FEAT; ++c) acc = fmaf(wrow[c], wh[c * HH], acc);
        wfuse[gid] = acc;
    } else if (gid < 128 * 128 + 256) {
        int r = gid - 128 * 128;
        int half = r >> 7, h = r & 127;
        const float* wh = l1wh + half * FEAT * HH + h;
        float acc = (half == 1) ? l1bh[h] : 0.f;
#pragma unroll
        for (int c = 0; c < FEAT; ++c) acc = fmaf(b_pre[c], wh[c * HH], acc);
        bfuse[r] = acc;
    } else if (gid < 128 * 128 + 256 + 256 * 64) {
        int i = gid - (128 * 128 + 256);
        int k = i >> 6, c = i & 63;
        wt[c * 256 + k] = f2b(ffw2[i]);
    }
}

// ---------------- Edge sort: key = src_octant(8) * 469 + dst_page(469) ----------------
__global__ void k_hist(const int* __restrict__ ei, unsigned* __restrict__ hist) {
    int e = blockIdx.x * 256 + threadIdx.x;
    if (e >= EE) return;
    int src = ei[e], dst = ei[EE + e];
    int key = (src * 8 / NN) * NPAGE + (dst >> 6);
    atomicAdd(&hist[key], 1u);
}

__global__ __launch_bounds__(1024) void k_scan(const unsigned* __restrict__ hist,
                                               unsigned* __restrict__ cursor) {
    __shared__ unsigned bs[1024];
    int t = threadIdx.x;
    int base = t * 4;
    unsigned v[4];
    unsigned s = 0;
#pragma unroll
    for (int j = 0; j < 4; ++j) {
        int i = base + j;
        unsigned h = (i < NB) ? hist[i] : 0u;
        v[j] = s;
        s += h;
    }
    bs[t] = s;
    __syncthreads();
    for (int off = 1; off < 1024; off <<= 1) {
        unsigned add = (t >= off) ? bs[t - off] : 0u;
        __syncthreads();
        bs[t] += add;
        __syncthreads();
    }
    unsigned excl = bs[t] - s;
#pragma unroll
    for (int j = 0; j < 4; ++j) {
        int i = base + j;
        if (i < NB) cursor[i] = excl + v[j];
    }
}

__global__ void k_scatter(const int* __restrict__ ei, unsigned* __restrict__ cursor,
                          int* __restrict__ ssrc, int* __restrict__ sdst,
                          int* __restrict__ seid) {
    int e = blockIdx.x * 256 + threadIdx.x;
    if (e >= EE) return;
    int src = ei[e], dst = ei[EE + e];
    int key = (src * 8 / NN) * NPAGE + (dst >> 6);
    unsigned pos = atomicAdd(&cursor[key], 1u);
    ssrc[pos] = src;
    sdst[pos] = dst;
    seid[pos] = e;
}

// ---------------- K3/K5: Gb = bf16(feat@wh[0:FIN] + gb), S = feat@wh[FIN:] + sb ----------------
template <int FIN>
__global__ void k_gs_gemm(const float* __restrict__ feat, const float* __restrict__ wh,
                          const float* __restrict__ gb, const float* __restrict__ sb,
                          unsigned short* __restrict__ Gb, float* __restrict__ S) {
    __shared__ float ft[16][FIN + 4];
    int nb = blockIdx.x * 16;
    int t = threadIdx.x;
    for (int idx = t; idx < 16 * FIN; idx += 256) {
        int n = idx / FIN, j = idx % FIN;
        ft[n][j] = feat[(nb + n) * FIN + j];
    }
    __syncthreads();
    int h = t & 127, g = t >> 7;
    float accG[8], accS[8];
#pragma unroll
    for (int i = 0; i < 8; ++i) { accG[i] = 0.f; accS[i] = 0.f; }
#pragma unroll 4
    for (int j = 0; j < FIN; ++j) {
        float wA = wh[j * HH + h];
        float wB = wh[(FIN + j) * HH + h];
#pragma unroll
        for (int i = 0; i < 8; ++i) {
            float f = ft[g + 2 * i][j];
            accG[i] = fmaf(f, wA, accG[i]);
            accS[i] = fmaf(f, wB, accS[i]);
        }
    }
    float gbv = gb ? gb[h] : 0.f;
    float sbv = sb[h];
#pragma unroll
    for (int i = 0; i < 8; ++i) {
        int n = nb + g + 2 * i;
        Gb[n * HH + h] = f2b(accG[i] + gbv);
        S[n * HH + h] = accS[i] + sbv;
    }
}

// ---------------- K4: layer1: h1 = mean_k relu(d1_k*G1[a_k] + S1) ----------------
__global__ void k_layer1(const unsigned* __restrict__ G1u, const float* __restrict__ S1,
                         const float* __restrict__ d1, const int* __restrict__ amax,
                         float* __restrict__ h1) {
    int t = threadIdx.x;
    int n = blockIdx.x * 4 + (t >> 6);
    int l = t & 63;
    float2 sv = *(const float2*)(S1 + n * HH + 2 * l);
    float acc0 = 0.f, acc1 = 0.f;
    const int* arow = amax + n * KK;
    const float* drow = d1 + n * KK;
#pragma unroll
    for (int k = 0; k < KK; ++k) {
        int a = arow[k];
        float dk = drow[k];
        unsigned g = G1u[a * 64 + l];
        acc0 += fmaxf(fmaf(dk, blo(g), sv.x), 0.f);
        acc1 += fmaxf(fmaf(dk, bhi(g), sv.y), 0.f);
    }
    float2 r;
    r.x = acc0 * (1.0f / 25.0f);
    r.y = acc1 * (1.0f / 25.0f);
    *(float2*)(h1 + n * HH + 2 * l) = r;
}

// ---------------- K6: layer2 pos + norm + w_lin, fused: hl (N,128) ----------------
__global__ __launch_bounds__(256) void k_xpos2(
    const unsigned* __restrict__ G2u, const float* __restrict__ S2,
    const float* __restrict__ d2, const int* __restrict__ amax,
    const float* __restrict__ wp, const float* __restrict__ bp,
    const float* __restrict__ wlin, const float* __restrict__ blin,
    float* __restrict__ hl) {
    __shared__ float xs[28];
    int t = threadIdx.x;
    int n = blockIdx.x;
    int w = t >> 6, l = t & 63;
    float2 sv = *(const float2*)(S2 + n * HH + 2 * l);
    float2 wpv = *(const float2*)(wp + 2 * l);
    float bpv = bp[0];
    const int* arow = amax + n * KK;
    const float* drow = d2 + n * KK;
    int kcnt = (w == 0) ? 7 : 6;
    unsigned gv[7];
    float dk[7];
#pragma unroll
    for (int j = 0; j < 7; ++j) {
        if (j < kcnt) {
            int k = w + 4 * j;
            int a = arow[k];
            gv[j] = G2u[a * 64 + l];
            dk[j] = drow[k];
        }
    }
    float v[7];
#pragma unroll
    for (int j = 0; j < 7; ++j) {
        if (j < kcnt) {
            v[j] = fmaxf(fmaf(dk[j], blo(gv[j]), sv.x), 0.f) * wpv.x +
                   fmaxf(fmaf(dk[j], bhi(gv[j]), sv.y), 0.f) * wpv.y;
        }
    }
#pragma unroll
    for (int s = 1; s < 64; s <<= 1) {
#pragma unroll
        for (int j = 0; j < 7; ++j) {
            if (j < kcnt) v[j] += __shfl_xor(v[j], s, 64);
        }
    }
    if (l == 0) {
#pragma unroll
        for (int j = 0; j < 7; ++j) {
            if (j < kcnt) xs[w + 4 * j] = v[j] + bpv;
        }
    }
    __syncthreads();
    if (t < HH) {
        float ss = 0.f;
#pragma unroll
        for (int k = 0; k < KK; ++k) { float x = xs[k]; ss = fmaf(x, x, ss); }
        float inv = 1.0f / fmaxf(sqrtf(ss), 1e-12f);
        float acc = blin[t];
#pragma unroll
        for (int k = 0; k < KK; ++k) {
            float x = fmaxf(xs[k], 0.f) * inv;
            acc = fmaf(x, wlin[k * HH + t], acc);
        }
        hl[n * HH + t] = fmaxf(acc, 0.f);
    }
}

// ---------------- K7: ab[n][0..511] = hl@W1top | hl@W1bot + ff_b1 (bf16 out) ----------------
__global__ void k_ab(const float* __restrict__ hl, const float* __restrict__ ffw1,
                     const float* __restrict__ ffb1, unsigned short* __restrict__ ab) {
    __shared__ float ht[16][132];
    int bc = blockIdx.x & 3;
    int nb = (blockIdx.x >> 2) * 16;
    int t = threadIdx.x;
    for (int idx = t; idx < 16 * HH; idx += 256) {
        int n = idx >> 7, j = idx & 127;
        ht[n][j] = hl[(nb + n) * HH + j];
    }
    __syncthreads();
    int c = t & 127, g = t >> 7;
    int c0 = bc * 128 + c;
    int rowoff = (c0 < 256) ? 0 : 128;
    int col = c0 & 255;
    float acc[8];
#pragma unroll
    for (int i = 0; i < 8; ++i) acc[i] = 0.f;
#pragma unroll 4
    for (int j = 0; j < HH; ++j) {
        float w = ffw1[(rowoff + j) * 256 + col];
#pragma unroll
        for (int i = 0; i < 8; ++i) acc[i] = fmaf(ht[g + 2 * i][j], w, acc[i]);
    }
    float bias = (c0 >= 256) ? ffb1[col] : 0.f;
#pragma unroll
    for (int i = 0; i < 8; ++i) {
        int n = nb + g + 2 * i;
        ab[n * 512 + c0] = f2b(acc[i] + bias);
    }
}

// ---------------- K8: sorted edges via MFMA, XCD-pinned ----------------
// grid = 3752 = 8*469; block b -> XCD (b&7) handles sorted range (b&7)*469+(b>>3).
__global__ __launch_bounds__(256) void k_edge_mfma(
    const unsigned short* __restrict__ abf, const int* __restrict__ ssrc,
    const int* __restrict__ sdst, const int* __restrict__ seid,
    const unsigned short* __restrict__ wtb, const float* __restrict__ ffb2,
    float* __restrict__ out) {
    int t = threadIdx.x;
    int l = t & 63;
    int bid = blockIdx.x;
    int blk = (bid & 7) * NPAGE + (bid >> 3);
    int tb = blk * 128 + (t >> 6) * 32;
    int erow = l & 31;
    int khalf = (l >> 5) * 8;
    int idx = tb + erow;
    int cidx = (idx < EE) ? idx : (EE - 1);
    int src = ssrc[cidx];
    int dst = sdst[cidx];
    int eid = seid[cidx];
    const unsigned short* ap = abf + (size_t)src * 512;
    const unsigned short* bp = abf + (size_t)dst * 512 + 256;
    const unsigned short* w0 = wtb + erow * 256 + khalf;
    const unsigned short* w1 = w0 + 32 * 256;

    f32x16 acc0, acc1;
#pragma unroll
    for (int i = 0; i < 16; ++i) { acc0[i] = 0.f; acc1[i] = 0.f; }

#pragma unroll 2
    for (int kt = 0; kt < 16; ++kt) {
        int k0 = kt * 16 + khalf;
        uint4 av = *(const uint4*)(ap + k0);
        uint4 bv = *(const uint4*)(bp + k0);
        unsigned ua[4] = {av.x, av.y, av.z, av.w};
        unsigned ub[4] = {bv.x, bv.y, bv.z, bv.w};
        bf16x8 af;
#pragma unroll
        for (int q = 0; q < 4; ++q) {
            float a0 = blo(ua[q]), a1 = bhi(ua[q]);
            float b0 = blo(ub[q]), b1 = bhi(ub[q]);
            af[2 * q]     = (__bf16)fmaxf(a0 + b0, 0.f);
            af[2 * q + 1] = (__bf16)fmaxf(a1 + b1, 0.f);
        }
        bf16x8 bf0 = *(const bf16x8*)(w0 + kt * 16);
        bf16x8 bf1 = *(const bf16x8*)(w1 + kt * 16);
        acc0 = __builtin_amdgcn_mfma_f32_32x32x16_bf16(af, bf0, acc0, 0, 0, 0);
        acc1 = __builtin_amdgcn_mfma_f32_32x32x16_bf16(af, bf1, acc1, 0, 0, 0);
    }

    int col = erow;
    float bias0 = ffb2[col], bias1 = ffb2[col + 32];
    int rbase = 4 * (l >> 5);
#pragma unroll
    for (int r = 0; r < 16; ++r) {
        int row = (r & 3) + 8 * (r >> 2) + rbase;
        int eidr = __shfl(eid, row, 64);
        if (tb + row < EE) {
            size_t o = (size_t)eidr * 64;
            out[o + col] = acc0[r] + bias0;
            out[o + 32 + col] = acc1[r] + bias1;
        }
    }
}

extern "C" void kernel_launch(void* const* d_in, const int* in_sizes, int n_in,
                              void* d_out, int out_size, void* d_ws, size_t ws_size,
                              hipStream_t stream) {
    const float* x     = (const float*)d_in[0];
    const float* dmax  = (const float*)d_in[1];
    const int*   amax  = (const int*)d_in[2];
    const int*   ei    = (const int*)d_in[3];
    const float* w_pre = (const float*)d_in[5];
    const float* b_pre = (const float*)d_in[6];
    const float* l1w1  = (const float*)d_in[7];
    const float* l1b1  = (const float*)d_in[8];
    const float* l1w2  = (const float*)d_in[9];
    const float* l1b2  = (const float*)d_in[10];
    const float* l1wh  = (const float*)d_in[11];
    const float* l1bh  = (const float*)d_in[12];
    const float* l2w1  = (const float*)d_in[15];
    const float* l2b1  = (const float*)d_in[16];
    const float* l2w2  = (const float*)d_in[17];
    const float* l2b2  = (const float*)d_in[18];
    const float* l2wh  = (const float*)d_in[19];
    const float* l2bh  = (const float*)d_in[20];
    const float* l2wp  = (const float*)d_in[21];
    const float* l2bp  = (const float*)d_in[22];
    const float* wlin  = (const float*)d_in[23];
    const float* blin  = (const float*)d_in[24];
    const float* ffw1  = (const float*)d_in[25];
    const float* ffb1  = (const float*)d_in[26];
    const float* ffw2  = (const float*)d_in[27];
    const float* ffb2  = (const float*)d_in[28];

    float* ws = (float*)d_ws;
    // Layout (float offsets):
    //   d1@0 (.75M)  d2@.75M (.75M)
    //   Gb(ushort)@1.5M (1.92M fl)  S@3.5M (3.84M fl)
    //   h1@7.5M (3.84M)  hl@11.5M (3.84M)
    //   wfuse@15.5M  bfuse@15.52M  wt(ushort)@15.53M
    //   ssrc@16.0M  sdst@16.5M  seid@17.0M  (NEPAD ints each)
    //   hist@17.5M  cursor@17.51M
    //   ab(ushort)@0 (7.68M fl) — overlaps phase-A region, dead by k_ab
    float* d1 = ws + 0;
    float* d2 = ws + 750000;
    unsigned short* Gb = (unsigned short*)(ws + 1500000);
    float* S  = ws + 3500000;
    float* h1 = ws + 7500000;
    float* hl = ws + 11500000;
    float* wfuse = ws + 15500000;
    float* bfuse = ws + 15520000;
    unsigned short* wt = (unsigned short*)(ws + 15530000);
    int* ssrc = (int*)(ws + 16000000);
    int* sdst = (int*)(ws + 16500000);
    int* seid = (int*)(ws + 17000000);
    unsigned* hist = (unsigned*)(ws + 17500000);
    unsigned* cursor = (unsigned*)(ws + 17510000);
    unsigned short* ab = (unsigned short*)ws;
    float* out = (float*)d_out;

    // Edge sort pipeline (only needs ei)
    hipMemsetAsync(hist, 0, NB * sizeof(unsigned), stream);
    k_hist<<<(EE + 255) / 256, 256, 0, stream>>>(ei, hist);
    k_scan<<<1, 1024, 0, stream>>>(hist, cursor);
    k_scatter<<<(EE + 255) / 256, 256, 0, stream>>>(ei, cursor, ssrc, sdst, seid);

    // Node pipeline
    k_dmlp<<<(NN * KK + 255) / 256, 256, 0, stream>>>(dmax, l1w1, l1b1, l1w2, l1b2,
                                                      l2w1, l2b1, l2w2, l2b2, d1, d2);
    k_wprep<<<129, 256, 0, stream>>>(w_pre, b_pre, l1wh, l1bh, ffw2, wfuse, bfuse, wt);
    k_gs_gemm<IN_F><<<NN / 16, 256, 0, stream>>>(x, wfuse, bfuse, bfuse + 128, Gb, S);
    k_layer1<<<NN / 4, 256, 0, stream>>>((const unsigned*)Gb, S, d1, amax, h1);
    k_gs_gemm<HH><<<NN / 16, 256, 0, stream>>>(h1, l2wh, nullptr, l2bh, Gb, S);
    k_xpos2<<<NN, 256, 0, stream>>>((const unsigned*)Gb, S, d2, amax, l2wp, l2bp,
                                    wlin, blin, hl);
    k_ab<<<(NN / 16) * 4, 256, 0, stream>>>(hl, ffw1, ffb1, ab);

    // Sorted, XCD-pinned edge GEMM
    k_edge_mfma<<<8 * NPAGE, 256, 0, stream>>>(ab, ssrc, sdst, seid, wt, ffb2, out);
}

// Round 6
// 457.048 us; speedup vs baseline: 1.0075x; 1.0075x over previous
//
#include <hip/hip_runtime.h>
#include <hip/hip_bf16.h>
#include <cmath>

#define NN 30000
#define KK 25
#define IN_F 64
#define FEAT 32
#define HH 128
#define OUTF 64
#define EE 480000
#define NPAGE 469              // dst pages of 64 nodes
#define NB (8 * NPAGE)         // sort buckets

typedef __attribute__((ext_vector_type(8))) __bf16 bf16x8;
typedef __attribute__((ext_vector_type(16))) float f32x16;

__device__ inline float u2f(unsigned u) { return __builtin_bit_cast(float, u); }
__device__ inline unsigned short f2b(float f) {
    __bf16 h = (__bf16)f;
    return __builtin_bit_cast(unsigned short, h);
}
__device__ inline float blo(unsigned u) { return u2f(u << 16); }
__device__ inline float bhi(unsigned u) { return u2f(u & 0xffff0000u); }

// ---------------- K2: d1,d2 = dist MLPs (N*K each) ----------------
__global__ void k_dmlp(const float* __restrict__ dmax,
                       const float* __restrict__ w1a, const float* __restrict__ b1a,
                       const float* __restrict__ w2a, const float* __restrict__ b2a,
                       const float* __restrict__ w1b, const float* __restrict__ b1b,
                       const float* __restrict__ w2b, const float* __restrict__ b2b,
                       float* __restrict__ d1, float* __restrict__ d2) {
    int i = blockIdx.x * 256 + threadIdx.x;
    if (i >= NN * KK) return;
    float dm = dmax[i];
    float a1 = 0.f, a2 = 0.f;
#pragma unroll 8
    for (int h = 0; h < HH; ++h) {
        float t1 = fmaxf(fmaf(dm, w1a[h], b1a[h]), 0.f);
        a1 = fmaf(t1, w2a[h], a1);
        float t2 = fmaxf(fmaf(dm, w1b[h], b1b[h]), 0.f);
        a2 = fmaf(t2, w2b[h], a2);
    }
    d1[i] = a1 + b2a[0];
    d2[i] = a2 + b2b[0];
}

// ---------------- K0: weight prep (fused w_pre@l1wh, ff_w2 transpose) ----------------
__global__ void k_wprep(const float* __restrict__ w_pre, const float* __restrict__ b_pre,
                        const float* __restrict__ l1wh, const float* __restrict__ l1bh,
                        const float* __restrict__ ffw2,
                        float* __restrict__ wfuse, float* __restrict__ bfuse,
                        unsigned short* __restrict__ wt) {
    int gid = blockIdx.x * 256 + threadIdx.x;
    if (gid < 128 * 128) {
        int j = gid >> 7, h = gid & 127;
        int half = j >> 6, jj = j & 63;
        const float* wrow = w_pre + jj * FEAT;
        const float* wh = l1wh + half * FEAT * HH + h;
        float acc = 0.f;
#pragma unroll
        for (int c = 0; c < FEAT; ++c) acc = fmaf(wrow[c], wh[c * HH], acc);
        wfuse[gid] = acc;
    } else if (gid < 128 * 128 + 256) {
        int r = gid - 128 * 128;
        int half = r >> 7, h = r & 127;
        const float* wh = l1wh + half * FEAT * HH + h;
        float acc = (half == 1) ? l1bh[h] : 0.f;
#pragma unroll
        for (int c = 0; c < FEAT; ++c) acc = fmaf(b_pre[c], wh[c * HH], acc);
        bfuse[r] = acc;
    } else if (gid < 128 * 128 + 256 + 256 * 64) {
        int i = gid - (128 * 128 + 256);
        int k = i >> 6, c = i & 63;
        wt[c * 256 + k] = f2b(ffw2[i]);
    }
}

// ---------------- Edge sort: key = src_octant(8) * 469 + dst_page(469) ----------------
__global__ void k_hist(const int* __restrict__ ei, unsigned* __restrict__ hist) {
    int e = blockIdx.x * 256 + threadIdx.x;
    if (e >= EE) return;
    int src = ei[e], dst = ei[EE + e];
    int key = (src * 8 / NN) * NPAGE + (dst >> 6);
    atomicAdd(&hist[key], 1u);
}

__global__ __launch_bounds__(1024) void k_scan(const unsigned* __restrict__ hist,
                                               unsigned* __restrict__ cursor) {
    __shared__ unsigned bs[1024];
    int t = threadIdx.x;
    int base = t * 4;
    unsigned v[4];
    unsigned s = 0;
#pragma unroll
    for (int j = 0; j < 4; ++j) {
        int i = base + j;
        unsigned h = (i < NB) ? hist[i] : 0u;
        v[j] = s;
        s += h;
    }
    bs[t] = s;
    __syncthreads();
    for (int off = 1; off < 1024; off <<= 1) {
        unsigned add = (t >= off) ? bs[t - off] : 0u;
        __syncthreads();
        bs[t] += add;
        __syncthreads();
    }
    unsigned excl = bs[t] - s;
#pragma unroll
    for (int j = 0; j < 4; ++j) {
        int i = base + j;
        if (i < NB) cursor[i] = excl + v[j];
    }
}

__global__ void k_scatter(const int* __restrict__ ei, unsigned* __restrict__ cursor,
                          uint4* __restrict__ sedge) {
    int e = blockIdx.x * 256 + threadIdx.x;
    if (e >= EE) return;
    int src = ei[e], dst = ei[EE + e];
    int key = (src * 8 / NN) * NPAGE + (dst >> 6);
    unsigned pos = atomicAdd(&cursor[key], 1u);
    sedge[pos] = make_uint4((unsigned)src, (unsigned)dst, (unsigned)e, 0u);
}

// ---------------- K3/K5: Gb = bf16(feat@wh[0:FIN] + gb), S = feat@wh[FIN:] + sb ----------------
template <int FIN>
__global__ void k_gs_gemm(const float* __restrict__ feat, const float* __restrict__ wh,
                          const float* __restrict__ gb, const float* __restrict__ sb,
                          unsigned short* __restrict__ Gb, float* __restrict__ S) {
    __shared__ float ft[16][FIN + 4];
    int nb = blockIdx.x * 16;
    int t = threadIdx.x;
    for (int idx = t; idx < 16 * FIN; idx += 256) {
        int n = idx / FIN, j = idx % FIN;
        ft[n][j] = feat[(nb + n) * FIN + j];
    }
    __syncthreads();
    int h = t & 127, g = t >> 7;
    float accG[8], accS[8];
#pragma unroll
    for (int i = 0; i < 8; ++i) { accG[i] = 0.f; accS[i] = 0.f; }
#pragma unroll 4
    for (int j = 0; j < FIN; ++j) {
        float wA = wh[j * HH + h];
        float wB = wh[(FIN + j) * HH + h];
#pragma unroll
        for (int i = 0; i < 8; ++i) {
            float f = ft[g + 2 * i][j];
            accG[i] = fmaf(f, wA, accG[i]);
            accS[i] = fmaf(f, wB, accS[i]);
        }
    }
    float gbv = gb ? gb[h] : 0.f;
    float sbv = sb[h];
#pragma unroll
    for (int i = 0; i < 8; ++i) {
        int n = nb + g + 2 * i;
        Gb[n * HH + h] = f2b(accG[i] + gbv);
        S[n * HH + h] = accS[i] + sbv;
    }
}

// ---------------- K4: layer1: h1 = mean_k relu(d1_k*G1[a_k] + S1) ----------------
__global__ void k_layer1(const unsigned* __restrict__ G1u, const float* __restrict__ S1,
                         const float* __restrict__ d1, const int* __restrict__ amax,
                         float* __restrict__ h1) {
    int t = threadIdx.x;
    int n = blockIdx.x * 4 + (t >> 6);
    int l = t & 63;
    float2 sv = *(const float2*)(S1 + n * HH + 2 * l);
    float acc0 = 0.f, acc1 = 0.f;
    const int* arow = amax + n * KK;
    const float* drow = d1 + n * KK;
#pragma unroll
    for (int k = 0; k < KK; ++k) {
        int a = arow[k];
        float dk = drow[k];
        unsigned g = G1u[a * 64 + l];
        acc0 += fmaxf(fmaf(dk, blo(g), sv.x), 0.f);
        acc1 += fmaxf(fmaf(dk, bhi(g), sv.y), 0.f);
    }
    float2 r;
    r.x = acc0 * (1.0f / 25.0f);
    r.y = acc1 * (1.0f / 25.0f);
    *(float2*)(h1 + n * HH + 2 * l) = r;
}

// ---------------- K6: layer2 pos + norm + w_lin, fused: hl (N,128) ----------------
__global__ __launch_bounds__(256) void k_xpos2(
    const unsigned* __restrict__ G2u, const float* __restrict__ S2,
    const float* __restrict__ d2, const int* __restrict__ amax,
    const float* __restrict__ wp, const float* __restrict__ bp,
    const float* __restrict__ wlin, const float* __restrict__ blin,
    float* __restrict__ hl) {
    __shared__ float xs[28];
    int t = threadIdx.x;
    int n = blockIdx.x;
    int w = t >> 6, l = t & 63;
    float2 sv = *(const float2*)(S2 + n * HH + 2 * l);
    float2 wpv = *(const float2*)(wp + 2 * l);
    float bpv = bp[0];
    const int* arow = amax + n * KK;
    const float* drow = d2 + n * KK;
    int kcnt = (w == 0) ? 7 : 6;
    unsigned gv[7];
    float dk[7];
#pragma unroll
    for (int j = 0; j < 7; ++j) {
        if (j < kcnt) {
            int k = w + 4 * j;
            int a = arow[k];
            gv[j] = G2u[a * 64 + l];
            dk[j] = drow[k];
        }
    }
    float v[7];
#pragma unroll
    for (int j = 0; j < 7; ++j) {
        if (j < kcnt) {
            v[j] = fmaxf(fmaf(dk[j], blo(gv[j]), sv.x), 0.f) * wpv.x +
                   fmaxf(fmaf(dk[j], bhi(gv[j]), sv.y), 0.f) * wpv.y;
        }
    }
#pragma unroll
    for (int s = 1; s < 64; s <<= 1) {
#pragma unroll
        for (int j = 0; j < 7; ++j) {
            if (j < kcnt) v[j] += __shfl_xor(v[j], s, 64);
        }
    }
    if (l == 0) {
#pragma unroll
        for (int j = 0; j < 7; ++j) {
            if (j < kcnt) xs[w + 4 * j] = v[j] + bpv;
        }
    }
    __syncthreads();
    if (t < HH) {
        float ss = 0.f;
#pragma unroll
        for (int k = 0; k < KK; ++k) { float x = xs[k]; ss = fmaf(x, x, ss); }
        float inv = 1.0f / fmaxf(sqrtf(ss), 1e-12f);
        float acc = blin[t];
#pragma unroll
        for (int k = 0; k < KK; ++k) {
            float x = fmaxf(xs[k], 0.f) * inv;
            acc = fmaf(x, wlin[k * HH + t], acc);
        }
        hl[n * HH + t] = fmaxf(acc, 0.f);
    }
}

// ---------------- K7: ab[n][0..511] = hl@W1top | hl@W1bot + ff_b1 (bf16 out) ----------------
__global__ void k_ab(const float* __restrict__ hl, const float* __restrict__ ffw1,
                     const float* __restrict__ ffb1, unsigned short* __restrict__ ab) {
    __shared__ float ht[16][132];
    int bc = blockIdx.x & 3;
    int nb = (blockIdx.x >> 2) * 16;
    int t = threadIdx.x;
    for (int idx = t; idx < 16 * HH; idx += 256) {
        int n = idx >> 7, j = idx & 127;
        ht[n][j] = hl[(nb + n) * HH + j];
    }
    __syncthreads();
    int c = t & 127, g = t >> 7;
    int c0 = bc * 128 + c;
    int rowoff = (c0 < 256) ? 0 : 128;
    int col = c0 & 255;
    float acc[8];
#pragma unroll
    for (int i = 0; i < 8; ++i) acc[i] = 0.f;
#pragma unroll 4
    for (int j = 0; j < HH; ++j) {
        float w = ffw1[(rowoff + j) * 256 + col];
#pragma unroll
        for (int i = 0; i < 8; ++i) acc[i] = fmaf(ht[g + 2 * i][j], w, acc[i]);
    }
    float bias = (c0 >= 256) ? ffb1[col] : 0.f;
#pragma unroll
    for (int i = 0; i < 8; ++i) {
        int n = nb + g + 2 * i;
        ab[n * 512 + c0] = f2b(acc[i] + bias);
    }
}

// ---------------- K8: sorted edges via MFMA, XCD-pinned, reg-double-buffered ----------------
#define DO_PAIR(ua4, ub4, kt) { \
    unsigned ua_[4] = {ua4.x, ua4.y, ua4.z, ua4.w}; \
    unsigned ub_[4] = {ub4.x, ub4.y, ub4.z, ub4.w}; \
    bf16x8 af_; \
    _Pragma("unroll") \
    for (int q = 0; q < 4; ++q) { \
        float a0_ = blo(ua_[q]), a1_ = bhi(ua_[q]); \
        float b0_ = blo(ub_[q]), b1_ = bhi(ub_[q]); \
        af_[2 * q]     = (__bf16)fmaxf(a0_ + b0_, 0.f); \
        af_[2 * q + 1] = (__bf16)fmaxf(a1_ + b1_, 0.f); \
    } \
    bf16x8 bf0_ = *(const bf16x8*)(w0 + (kt) * 16); \
    bf16x8 bf1_ = *(const bf16x8*)(w1 + (kt) * 16); \
    acc0 = __builtin_amdgcn_mfma_f32_32x32x16_bf16(af_, bf0_, acc0, 0, 0, 0); \
    acc1 = __builtin_amdgcn_mfma_f32_32x32x16_bf16(af_, bf1_, acc1, 0, 0, 0); \
}

#define LDG(pa0, pb0, pa1, pb1, g) { \
    pa0 = *(const uint4*)(ap + (g) * 32); \
    pb0 = *(const uint4*)(bp + (g) * 32); \
    pa1 = *(const uint4*)(ap + (g) * 32 + 16); \
    pb1 = *(const uint4*)(bp + (g) * 32 + 16); \
}

#define STANZA(ca0, cb0, ca1, cb1, na0, nb0, na1, nb1, g) { \
    if ((g) < 7) LDG(na0, nb0, na1, nb1, (g) + 1); \
    DO_PAIR(ca0, cb0, 2 * (g)); \
    DO_PAIR(ca1, cb1, 2 * (g) + 1); \
}

__global__ __launch_bounds__(256) void k_edge_mfma(
    const unsigned short* __restrict__ abf, const uint4* __restrict__ sedge,
    const unsigned short* __restrict__ wtb, const float* __restrict__ ffb2,
    float* __restrict__ out) {
    int t = threadIdx.x;
    int l = t & 63;
    int bid = blockIdx.x;
    int blk = (bid & 7) * NPAGE + (bid >> 3);
    int tb = blk * 128 + (t >> 6) * 32;
    int erow = l & 31;
    int khalf = (l >> 5) * 8;
    int idx = tb + erow;
    int cidx = (idx < EE) ? idx : (EE - 1);
    uint4 rec = sedge[cidx];
    int src = (int)rec.x;
    int dst = (int)rec.y;
    int eid = (int)rec.z;
    const unsigned short* ap = abf + (size_t)src * 512 + khalf;
    const unsigned short* bp = abf + (size_t)dst * 512 + 256 + khalf;
    const unsigned short* w0 = wtb + erow * 256 + khalf;
    const unsigned short* w1 = w0 + 32 * 256;

    f32x16 acc0, acc1;
#pragma unroll
    for (int i = 0; i < 16; ++i) { acc0[i] = 0.f; acc1[i] = 0.f; }

    uint4 Aa0, Ab0, Aa1, Ab1, Ba0, Bb0, Ba1, Bb1;
    LDG(Aa0, Ab0, Aa1, Ab1, 0);
    STANZA(Aa0, Ab0, Aa1, Ab1, Ba0, Bb0, Ba1, Bb1, 0);
    STANZA(Ba0, Bb0, Ba1, Bb1, Aa0, Ab0, Aa1, Ab1, 1);
    STANZA(Aa0, Ab0, Aa1, Ab1, Ba0, Bb0, Ba1, Bb1, 2);
    STANZA(Ba0, Bb0, Ba1, Bb1, Aa0, Ab0, Aa1, Ab1, 3);
    STANZA(Aa0, Ab0, Aa1, Ab1, Ba0, Bb0, Ba1, Bb1, 4);
    STANZA(Ba0, Bb0, Ba1, Bb1, Aa0, Ab0, Aa1, Ab1, 5);
    STANZA(Aa0, Ab0, Aa1, Ab1, Ba0, Bb0, Ba1, Bb1, 6);
    STANZA(Ba0, Bb0, Ba1, Bb1, Aa0, Ab0, Aa1, Ab1, 7);

    int col = erow;
    float bias0 = ffb2[col], bias1 = ffb2[col + 32];
    int rbase = 4 * (l >> 5);
#pragma unroll
    for (int r = 0; r < 16; ++r) {
        int row = (r & 3) + 8 * (r >> 2) + rbase;
        int eidr = __shfl(eid, row, 64);
        if (tb + row < EE) {
            size_t o = (size_t)eidr * 64;
            out[o + col] = acc0[r] + bias0;
            out[o + 32 + col] = acc1[r] + bias1;
        }
    }
}

extern "C" void kernel_launch(void* const* d_in, const int* in_sizes, int n_in,
                              void* d_out, int out_size, void* d_ws, size_t ws_size,
                              hipStream_t stream) {
    const float* x     = (const float*)d_in[0];
    const float* dmax  = (const float*)d_in[1];
    const int*   amax  = (const int*)d_in[2];
    const int*   ei    = (const int*)d_in[3];
    const float* w_pre = (const float*)d_in[5];
    const float* b_pre = (const float*)d_in[6];
    const float* l1w1  = (const float*)d_in[7];
    const float* l1b1  = (const float*)d_in[8];
    const float* l1w2  = (const float*)d_in[9];
    const float* l1b2  = (const float*)d_in[10];
    const float* l1wh  = (const float*)d_in[11];
    const float* l1bh  = (const float*)d_in[12];
    const float* l2w1  = (const float*)d_in[15];
    const float* l2b1  = (const float*)d_in[16];
    const float* l2w2  = (const float*)d_in[17];
    const float* l2b2  = (const float*)d_in[18];
    const float* l2wh  = (const float*)d_in[19];
    const float* l2bh  = (const float*)d_in[20];
    const float* l2wp  = (const float*)d_in[21];
    const float* l2bp  = (const float*)d_in[22];
    const float* wlin  = (const float*)d_in[23];
    const float* blin  = (const float*)d_in[24];
    const float* ffw1  = (const float*)d_in[25];
    const float* ffb1  = (const float*)d_in[26];
    const float* ffw2  = (const float*)d_in[27];
    const float* ffb2  = (const float*)d_in[28];

    float* ws = (float*)d_ws;
    // Layout (float offsets):
    //   d1@0 (.75M)  d2@.75M (.75M)
    //   Gb(ushort)@1.5M (1.92M fl)  S@3.5M (3.84M fl)
    //   h1@7.5M (3.84M)  hl@11.5M (3.84M)
    //   wfuse@15.5M  bfuse@15.52M  wt(ushort)@15.53M
    //   hist@15.6M  cursor@15.61M
    //   ab(ushort)@0 (7.68M fl) — overlaps d*/Gb/S (dead by k_ab)
    //   sedge(uint4)@11.5M (1.92M fl) — overlaps hl (dead after k_ab; scatter runs after k_ab)
    float* d1 = ws + 0;
    float* d2 = ws + 750000;
    unsigned short* Gb = (unsigned short*)(ws + 1500000);
    float* S  = ws + 3500000;
    float* h1 = ws + 7500000;
    float* hl = ws + 11500000;
    float* wfuse = ws + 15500000;
    float* bfuse = ws + 15520000;
    unsigned short* wt = (unsigned short*)(ws + 15530000);
    unsigned* hist = (unsigned*)(ws + 15600000);
    unsigned* cursor = (unsigned*)(ws + 15610000);
    uint4* sedge = (uint4*)(ws + 11500000);
    unsigned short* ab = (unsigned short*)ws;
    float* out = (float*)d_out;

    // Node pipeline
    k_dmlp<<<(NN * KK + 255) / 256, 256, 0, stream>>>(dmax, l1w1, l1b1, l1w2, l1b2,
                                                      l2w1, l2b1, l2w2, l2b2, d1, d2);
    k_wprep<<<129, 256, 0, stream>>>(w_pre, b_pre, l1wh, l1bh, ffw2, wfuse, bfuse, wt);
    k_gs_gemm<IN_F><<<NN / 16, 256, 0, stream>>>(x, wfuse, bfuse, bfuse + 128, Gb, S);
    k_layer1<<<NN / 4, 256, 0, stream>>>((const unsigned*)Gb, S, d1, amax, h1);
    k_gs_gemm<HH><<<NN / 16, 256, 0, stream>>>(h1, l2wh, nullptr, l2bh, Gb, S);
    k_xpos2<<<NN, 256, 0, stream>>>((const unsigned*)Gb, S, d2, amax, l2wp, l2bp,
                                    wlin, blin, hl);
    k_ab<<<(NN / 16) * 4, 256, 0, stream>>>(hl, ffw1, ffb1, ab);

    // Edge sort (after k_ab so sedge can reuse hl's region)
    hipMemsetAsync(hist, 0, NB * sizeof(unsigned), stream);
    k_hist<<<(EE + 255) / 256, 256, 0, stream>>>(ei, hist);
    k_scan<<<1, 1024, 0, stream>>>(hist, cursor);
    k_scatter<<<(EE + 255) / 256, 256, 0, stream>>>(ei, cursor, sedge);

    // Sorted, XCD-pinned edge GEMM
    k_edge_mfma<<<8 * NPAGE, 256, 0, stream>>>(ab, sedge, wt, ffb2, out);
}

// Round 7
// 425.072 us; speedup vs baseline: 1.0833x; 1.0752x over previous
//
#include <hip/hip_runtime.h>
#include <hip/hip_bf16.h>
#include <cmath>

#define NN 30000
#define KK 25
#define IN_F 64
#define FEAT 32
#define HH 128
#define OUTF 64
#define EE 480000
#define NPAGE 469              // dst pages of 64 nodes
#define NB (8 * NPAGE)         // sort buckets

typedef __attribute__((ext_vector_type(8))) __bf16 bf16x8;
typedef __attribute__((ext_vector_type(8))) _Float16 fp16x8;
typedef __attribute__((ext_vector_type(2))) _Float16 h2v;
typedef __attribute__((ext_vector_type(16))) float f32x16;

__device__ inline float u2f(unsigned u) { return __builtin_bit_cast(float, u); }
__device__ inline unsigned short f2b(float f) {
    __bf16 h = (__bf16)f;
    return __builtin_bit_cast(unsigned short, h);
}
__device__ inline unsigned short f2h(float f) {
    _Float16 h = (_Float16)f;
    return __builtin_bit_cast(unsigned short, h);
}
__device__ inline float blo(unsigned u) { return u2f(u << 16); }
__device__ inline float bhi(unsigned u) { return u2f(u & 0xffff0000u); }

// packed fp16: relu(a + b) on 2 lanes -> v_pk_add_f16 + v_pk_max_f16
__device__ inline unsigned hrelu2(unsigned a, unsigned b) {
    h2v x = __builtin_bit_cast(h2v, a);
    h2v y = __builtin_bit_cast(h2v, b);
    h2v s = x + y;
    h2v z = {(_Float16)0.f, (_Float16)0.f};
    h2v r = __builtin_elementwise_max(s, z);
    return __builtin_bit_cast(unsigned, r);
}

// ---------------- K2: d1,d2 = dist MLPs (N*K each) ----------------
__global__ void k_dmlp(const float* __restrict__ dmax,
                       const float* __restrict__ w1a, const float* __restrict__ b1a,
                       const float* __restrict__ w2a, const float* __restrict__ b2a,
                       const float* __restrict__ w1b, const float* __restrict__ b1b,
                       const float* __restrict__ w2b, const float* __restrict__ b2b,
                       float* __restrict__ d1, float* __restrict__ d2) {
    int i = blockIdx.x * 256 + threadIdx.x;
    if (i >= NN * KK) return;
    float dm = dmax[i];
    float a1 = 0.f, a2 = 0.f;
#pragma unroll 8
    for (int h = 0; h < HH; ++h) {
        float t1 = fmaxf(fmaf(dm, w1a[h], b1a[h]), 0.f);
        a1 = fmaf(t1, w2a[h], a1);
        float t2 = fmaxf(fmaf(dm, w1b[h], b1b[h]), 0.f);
        a2 = fmaf(t2, w2b[h], a2);
    }
    d1[i] = a1 + b2a[0];
    d2[i] = a2 + b2b[0];
}

// ---------------- K0: weight prep (fused w_pre@l1wh, ff_w2 transpose fp16) ----------------
__global__ void k_wprep(const float* __restrict__ w_pre, const float* __restrict__ b_pre,
                        const float* __restrict__ l1wh, const float* __restrict__ l1bh,
                        const float* __restrict__ ffw2,
                        float* __restrict__ wfuse, float* __restrict__ bfuse,
                        unsigned short* __restrict__ wt) {
    int gid = blockIdx.x * 256 + threadIdx.x;
    if (gid < 128 * 128) {
        int j = gid >> 7, h = gid & 127;
        int half = j >> 6, jj = j & 63;
        const float* wrow = w_pre + jj * FEAT;
        const float* wh = l1wh + half * FEAT * HH + h;
        float acc = 0.f;
#pragma unroll
        for (int c = 0; c < FEAT; ++c) acc = fmaf(wrow[c], wh[c * HH], acc);
        wfuse[gid] = acc;
    } else if (gid < 128 * 128 + 256) {
        int r = gid - 128 * 128;
        int half = r >> 7, h = r & 127;
        const float* wh = l1wh + half * FEAT * HH + h;
        float acc = (half == 1) ? l1bh[h] : 0.f;
#pragma unroll
        for (int c = 0; c < FEAT; ++c) acc = fmaf(b_pre[c], wh[c * HH], acc);
        bfuse[r] = acc;
    } else if (gid < 128 * 128 + 256 + 256 * 64) {
        int i = gid - (128 * 128 + 256);
        int k = i >> 6, c = i & 63;
        wt[c * 256 + k] = f2h(ffw2[i]);
    }
}

// ---------------- Edge sort: key = src_octant(8) * 469 + dst_page(469) ----------------
// 8 edges per thread: 8 atomics in flight, vectorized reads.
__global__ void k_hist(const int* __restrict__ ei, unsigned* __restrict__ hist) {
    int base = (blockIdx.x * 256 + threadIdx.x) * 8;
    if (base >= EE) return;
    int4 s0 = *(const int4*)(ei + base);
    int4 s1 = *(const int4*)(ei + base + 4);
    int4 d0 = *(const int4*)(ei + EE + base);
    int4 d1 = *(const int4*)(ei + EE + base + 4);
    int ss[8] = {s0.x, s0.y, s0.z, s0.w, s1.x, s1.y, s1.z, s1.w};
    int dd[8] = {d0.x, d0.y, d0.z, d0.w, d1.x, d1.y, d1.z, d1.w};
#pragma unroll
    for (int j = 0; j < 8; ++j) {
        int key = (ss[j] * 8 / NN) * NPAGE + (dd[j] >> 6);
        atomicAdd(&hist[key], 1u);
    }
}

// single-wave scan (no block barriers)
__global__ __launch_bounds__(64) void k_scan(const unsigned* __restrict__ hist,
                                             unsigned* __restrict__ cursor) {
    int l = threadIdx.x;
    const int PER = 59;  // 64*59 = 3776 >= NB
    unsigned tot = 0;
    for (int j = 0; j < PER; ++j) {
        int i = l * PER + j;
        if (i < NB) tot += hist[i];
    }
    unsigned run = tot;
#pragma unroll
    for (int off = 1; off < 64; off <<= 1) {
        unsigned u = __shfl_up(run, off, 64);
        if (l >= off) run += u;
    }
    unsigned base = run - tot;
    for (int j = 0; j < PER; ++j) {
        int i = l * PER + j;
        if (i < NB) {
            cursor[i] = base;
            base += hist[i];
        }
    }
}

__global__ void k_scatter(const int* __restrict__ ei, unsigned* __restrict__ cursor,
                          uint4* __restrict__ sedge) {
    int base = (blockIdx.x * 256 + threadIdx.x) * 8;
    if (base >= EE) return;
    int4 s0 = *(const int4*)(ei + base);
    int4 s1 = *(const int4*)(ei + base + 4);
    int4 d0 = *(const int4*)(ei + EE + base);
    int4 d1 = *(const int4*)(ei + EE + base + 4);
    int ss[8] = {s0.x, s0.y, s0.z, s0.w, s1.x, s1.y, s1.z, s1.w};
    int dd[8] = {d0.x, d0.y, d0.z, d0.w, d1.x, d1.y, d1.z, d1.w};
    unsigned pp[8];
#pragma unroll
    for (int j = 0; j < 8; ++j) {
        int key = (ss[j] * 8 / NN) * NPAGE + (dd[j] >> 6);
        pp[j] = atomicAdd(&cursor[key], 1u);
    }
#pragma unroll
    for (int j = 0; j < 8; ++j)
        sedge[pp[j]] = make_uint4((unsigned)ss[j], (unsigned)dd[j], (unsigned)(base + j), 0u);
}

// ---------------- K3/K5: Gb = bf16(feat@wh[0:FIN] + gb), S = feat@wh[FIN:] + sb ----------------
template <int FIN>
__global__ void k_gs_gemm(const float* __restrict__ feat, const float* __restrict__ wh,
                          const float* __restrict__ gb, const float* __restrict__ sb,
                          unsigned short* __restrict__ Gb, float* __restrict__ S) {
    __shared__ float ft[16][FIN + 4];
    int nb = blockIdx.x * 16;
    int t = threadIdx.x;
    for (int idx = t; idx < 16 * FIN; idx += 256) {
        int n = idx / FIN, j = idx % FIN;
        ft[n][j] = feat[(nb + n) * FIN + j];
    }
    __syncthreads();
    int h = t & 127, g = t >> 7;
    float accG[8], accS[8];
#pragma unroll
    for (int i = 0; i < 8; ++i) { accG[i] = 0.f; accS[i] = 0.f; }
#pragma unroll 4
    for (int j = 0; j < FIN; ++j) {
        float wA = wh[j * HH + h];
        float wB = wh[(FIN + j) * HH + h];
#pragma unroll
        for (int i = 0; i < 8; ++i) {
            float f = ft[g + 2 * i][j];
            accG[i] = fmaf(f, wA, accG[i]);
            accS[i] = fmaf(f, wB, accS[i]);
        }
    }
    float gbv = gb ? gb[h] : 0.f;
    float sbv = sb[h];
#pragma unroll
    for (int i = 0; i < 8; ++i) {
        int n = nb + g + 2 * i;
        Gb[n * HH + h] = f2b(accG[i] + gbv);
        S[n * HH + h] = accS[i] + sbv;
    }
}

// ---------------- K4: layer1: h1 = mean_k relu(d1_k*G1[a_k] + S1) ----------------
__global__ void k_layer1(const unsigned* __restrict__ G1u, const float* __restrict__ S1,
                         const float* __restrict__ d1, const int* __restrict__ amax,
                         float* __restrict__ h1) {
    int t = threadIdx.x;
    int n = blockIdx.x * 4 + (t >> 6);
    int l = t & 63;
    float2 sv = *(const float2*)(S1 + n * HH + 2 * l);
    float acc0 = 0.f, acc1 = 0.f;
    const int* arow = amax + n * KK;
    const float* drow = d1 + n * KK;
#pragma unroll
    for (int k = 0; k < KK; ++k) {
        int a = arow[k];
        float dk = drow[k];
        unsigned g = G1u[a * 64 + l];
        acc0 += fmaxf(fmaf(dk, blo(g), sv.x), 0.f);
        acc1 += fmaxf(fmaf(dk, bhi(g), sv.y), 0.f);
    }
    float2 r;
    r.x = acc0 * (1.0f / 25.0f);
    r.y = acc1 * (1.0f / 25.0f);
    *(float2*)(h1 + n * HH + 2 * l) = r;
}

// ---------------- K6: layer2 pos + norm + w_lin, fused: hl (N,128) ----------------
__global__ __launch_bounds__(256) void k_xpos2(
    const unsigned* __restrict__ G2u, const float* __restrict__ S2,
    const float* __restrict__ d2, const int* __restrict__ amax,
    const float* __restrict__ wp, const float* __restrict__ bp,
    const float* __restrict__ wlin, const float* __restrict__ blin,
    float* __restrict__ hl) {
    __shared__ float xs[28];
    int t = threadIdx.x;
    int n = blockIdx.x;
    int w = t >> 6, l = t & 63;
    float2 sv = *(const float2*)(S2 + n * HH + 2 * l);
    float2 wpv = *(const float2*)(wp + 2 * l);
    float bpv = bp[0];
    const int* arow = amax + n * KK;
    const float* drow = d2 + n * KK;
    int kcnt = (w == 0) ? 7 : 6;
    unsigned gv[7];
    float dk[7];
#pragma unroll
    for (int j = 0; j < 7; ++j) {
        if (j < kcnt) {
            int k = w + 4 * j;
            int a = arow[k];
            gv[j] = G2u[a * 64 + l];
            dk[j] = drow[k];
        }
    }
    float v[7];
#pragma unroll
    for (int j = 0; j < 7; ++j) {
        if (j < kcnt) {
            v[j] = fmaxf(fmaf(dk[j], blo(gv[j]), sv.x), 0.f) * wpv.x +
                   fmaxf(fmaf(dk[j], bhi(gv[j]), sv.y), 0.f) * wpv.y;
        }
    }
#pragma unroll
    for (int s = 1; s < 64; s <<= 1) {
#pragma unroll
        for (int j = 0; j < 7; ++j) {
            if (j < kcnt) v[j] += __shfl_xor(v[j], s, 64);
        }
    }
    if (l == 0) {
#pragma unroll
        for (int j = 0; j < 7; ++j) {
            if (j < kcnt) xs[w + 4 * j] = v[j] + bpv;
        }
    }
    __syncthreads();
    if (t < HH) {
        float ss = 0.f;
#pragma unroll
        for (int k = 0; k < KK; ++k) { float x = xs[k]; ss = fmaf(x, x, ss); }
        float inv = 1.0f / fmaxf(sqrtf(ss), 1e-12f);
        float acc = blin[t];
#pragma unroll
        for (int k = 0; k < KK; ++k) {
            float x = fmaxf(xs[k], 0.f) * inv;
            acc = fmaf(x, wlin[k * HH + t], acc);
        }
        hl[n * HH + t] = fmaxf(acc, 0.f);
    }
}

// ---------------- K7: ab[n][0..511] = hl@W1top | hl@W1bot + ff_b1 (fp16 out) ----------------
__global__ void k_ab(const float* __restrict__ hl, const float* __restrict__ ffw1,
                     const float* __restrict__ ffb1, unsigned short* __restrict__ ab) {
    __shared__ float ht[16][132];
    int bc = blockIdx.x & 3;
    int nb = (blockIdx.x >> 2) * 16;
    int t = threadIdx.x;
    for (int idx = t; idx < 16 * HH; idx += 256) {
        int n = idx >> 7, j = idx & 127;
        ht[n][j] = hl[(nb + n) * HH + j];
    }
    __syncthreads();
    int c = t & 127, g = t >> 7;
    int c0 = bc * 128 + c;
    int rowoff = (c0 < 256) ? 0 : 128;
    int col = c0 & 255;
    float acc[8];
#pragma unroll
    for (int i = 0; i < 8; ++i) acc[i] = 0.f;
#pragma unroll 4
    for (int j = 0; j < HH; ++j) {
        float w = ffw1[(rowoff + j) * 256 + col];
#pragma unroll
        for (int i = 0; i < 8; ++i) acc[i] = fmaf(ht[g + 2 * i][j], w, acc[i]);
    }
    float bias = (c0 >= 256) ? ffb1[col] : 0.f;
#pragma unroll
    for (int i = 0; i < 8; ++i) {
        int n = nb + g + 2 * i;
        ab[n * 512 + c0] = f2h(acc[i] + bias);
    }
}

// ---------------- K8: sorted edges, LDS-staged coalesced, fp16 MFMA ----------------
// 512 blocks (2/CU), 256 thr (4 waves). Block loops over 128-edge tiles of its XCD's
// sorted range. Stage: row-contiguous loads (2 rows/instr), packed relu(a+b) -> LDS
// (XOR-swizzled). MFMA: A from LDS, W2 fragments in registers (loaded once).
__global__ __launch_bounds__(256, 2) void k_edge_mfma(
    const unsigned short* __restrict__ abf, const uint4* __restrict__ sedge,
    const unsigned short* __restrict__ wt, const float* __restrict__ ffb2,
    float* __restrict__ out) {
    __shared__ uint4 P[128 * 32];  // 64 KB: 128 rows x 256 fp16, swizzled
    int t = threadIdx.x;
    int l = t & 63;
    int w = t >> 6;
    int c = l & 31, kh = l >> 5;

    // W2 fragments, once per block (L1-resident table, amortized over ~8 tiles)
    fp16x8 wf0[16], wf1[16];
#pragma unroll
    for (int kt = 0; kt < 16; ++kt) {
        wf0[kt] = *(const fp16x8*)(wt + c * 256 + kt * 16 + kh * 8);
        wf1[kt] = *(const fp16x8*)(wt + (c + 32) * 256 + kt * 16 + kh * 8);
    }
    float bias0 = ffb2[c], bias1 = ffb2[c + 32];

    int xcd = blockIdx.x & 7;
    int slot = blockIdx.x >> 3;
    int seg = t & 31;   // 16B segment within a 512B row
    int rb = t >> 5;    // 0..7: row-within-round

    for (int tl = slot; tl < NPAGE; tl += 64) {
        int tb = (xcd * NPAGE + tl) * 128;
        // ---- stage 128 rows of relu(a+b), coalesced ----
#pragma unroll 4
        for (int r = 0; r < 16; ++r) {
            int row = r * 8 + rb;
            int pos = tb + row;
            uint4 rec = sedge[pos < EE ? pos : EE - 1];
            uint4 a = *(const uint4*)(abf + (size_t)rec.x * 512 + seg * 8);
            uint4 b = *(const uint4*)(abf + (size_t)rec.y * 512 + 256 + seg * 8);
            uint4 p;
            p.x = hrelu2(a.x, b.x);
            p.y = hrelu2(a.y, b.y);
            p.z = hrelu2(a.z, b.z);
            p.w = hrelu2(a.w, b.w);
            int col = (seg * 16) ^ ((row & 15) << 4);
            P[row * 32 + (col >> 4)] = p;
        }
        __syncthreads();
        // ---- MFMA: 32 edges x 64 cols per wave ----
        f32x16 acc0, acc1;
#pragma unroll
        for (int i = 0; i < 16; ++i) { acc0[i] = 0.f; acc1[i] = 0.f; }
        int wrow = w * 32 + c;
        int sw = (wrow & 15) << 4;
#pragma unroll
        for (int kt = 0; kt < 16; ++kt) {
            int col = (kt * 32 + kh * 16) ^ sw;
            fp16x8 af = __builtin_bit_cast(fp16x8, P[wrow * 32 + (col >> 4)]);
            acc0 = __builtin_amdgcn_mfma_f32_32x32x16_f16(af, wf0[kt], acc0, 0, 0, 0);
            acc1 = __builtin_amdgcn_mfma_f32_32x32x16_f16(af, wf1[kt], acc1, 0, 0, 0);
        }
        // ---- store (scatter by original eid; 2x128B segments per instr) ----
        int spos = tb + wrow;
        int eid = (int)sedge[spos < EE ? spos : EE - 1].z;
        int rbase = 4 * kh;
#pragma unroll
        for (int r = 0; r < 16; ++r) {
            int row = (r & 3) + 8 * (r >> 2) + rbase;  // 0..31 within wave tile
            int eidr = __shfl(eid, row, 64);
            if (tb + w * 32 + row < EE) {
                size_t o = (size_t)eidr * 64;
                out[o + c] = acc0[r] + bias0;
                out[o + 32 + c] = acc1[r] + bias1;
            }
        }
        __syncthreads();  // P reused next tile
    }
}

extern "C" void kernel_launch(void* const* d_in, const int* in_sizes, int n_in,
                              void* d_out, int out_size, void* d_ws, size_t ws_size,
                              hipStream_t stream) {
    const float* x     = (const float*)d_in[0];
    const float* dmax  = (const float*)d_in[1];
    const int*   amax  = (const int*)d_in[2];
    const int*   ei    = (const int*)d_in[3];
    const float* w_pre = (const float*)d_in[5];
    const float* b_pre = (const float*)d_in[6];
    const float* l1w1  = (const float*)d_in[7];
    const float* l1b1  = (const float*)d_in[8];
    const float* l1w2  = (const float*)d_in[9];
    const float* l1b2  = (const float*)d_in[10];
    const float* l1wh  = (const float*)d_in[11];
    const float* l1bh  = (const float*)d_in[12];
    const float* l2w1  = (const float*)d_in[15];
    const float* l2b1  = (const float*)d_in[16];
    const float* l2w2  = (const float*)d_in[17];
    const float* l2b2  = (const float*)d_in[18];
    const float* l2wh  = (const float*)d_in[19];
    const float* l2bh  = (const float*)d_in[20];
    const float* l2wp  = (const float*)d_in[21];
    const float* l2bp  = (const float*)d_in[22];
    const float* wlin  = (const float*)d_in[23];
    const float* blin  = (const float*)d_in[24];
    const float* ffw1  = (const float*)d_in[25];
    const float* ffb1  = (const float*)d_in[26];
    const float* ffw2  = (const float*)d_in[27];
    const float* ffb2  = (const float*)d_in[28];

    float* ws = (float*)d_ws;
    // Layout (float offsets):
    //   d1@0  d2@.75M  Gb(ushort)@1.5M  S@3.5M  h1@7.5M  hl@11.5M
    //   wfuse@15.5M  bfuse@15.52M  wt(ushort fp16)@15.53M  hist@15.6M  cursor@15.61M
    //   ab(ushort fp16)@0 (7.68M fl) — overlaps d*/Gb/S (dead by k_ab)
    //   sedge(uint4)@11.5M — overlaps hl (dead after k_ab; scatter runs after k_ab)
    float* d1 = ws + 0;
    float* d2 = ws + 750000;
    unsigned short* Gb = (unsigned short*)(ws + 1500000);
    float* S  = ws + 3500000;
    float* h1 = ws + 7500000;
    float* hl = ws + 11500000;
    float* wfuse = ws + 15500000;
    float* bfuse = ws + 15520000;
    unsigned short* wt = (unsigned short*)(ws + 15530000);
    unsigned* hist = (unsigned*)(ws + 15600000);
    unsigned* cursor = (unsigned*)(ws + 15610000);
    uint4* sedge = (uint4*)(ws + 11500000);
    unsigned short* ab = (unsigned short*)ws;
    float* out = (float*)d_out;

    // Histogram + scan early (independent of node pipeline)
    hipMemsetAsync(hist, 0, NB * sizeof(unsigned), stream);
    k_hist<<<(EE / 8 + 255) / 256, 256, 0, stream>>>(ei, hist);
    k_scan<<<1, 64, 0, stream>>>(hist, cursor);

    // Node pipeline
    k_dmlp<<<(NN * KK + 255) / 256, 256, 0, stream>>>(dmax, l1w1, l1b1, l1w2, l1b2,
                                                      l2w1, l2b1, l2w2, l2b2, d1, d2);
    k_wprep<<<129, 256, 0, stream>>>(w_pre, b_pre, l1wh, l1bh, ffw2, wfuse, bfuse, wt);
    k_gs_gemm<IN_F><<<NN / 16, 256, 0, stream>>>(x, wfuse, bfuse, bfuse + 128, Gb, S);
    k_layer1<<<NN / 4, 256, 0, stream>>>((const unsigned*)Gb, S, d1, amax, h1);
    k_gs_gemm<HH><<<NN / 16, 256, 0, stream>>>(h1, l2wh, nullptr, l2bh, Gb, S);
    k_xpos2<<<NN, 256, 0, stream>>>((const unsigned*)Gb, S, d2, amax, l2wp, l2bp,
                                    wlin, blin, hl);
    k_ab<<<(NN / 16) * 4, 256, 0, stream>>>(hl, ffw1, ffb1, ab);

    // Scatter after k_ab (sedge reuses hl region)
    k_scatter<<<(EE / 8 + 255) / 256, 256, 0, stream>>>(ei, cursor, sedge);

    // Sorted, XCD-pinned, LDS-staged edge GEMM
    k_edge_mfma<<<512, 256, 0, stream>>>(ab, sedge, wt, ffb2, out);
}

// Round 9
// 359.965 us; speedup vs baseline: 1.2792x; 1.1809x over previous
//
#include <hip/hip_runtime.h>
#include <hip/hip_bf16.h>
#include <cmath>

#define NN 30000
#define KK 25
#define IN_F 64
#define FEAT 32
#define HH 128
#define OUTF 64
#define EE 480000
#define NPAGE 469              // dst pages of 64 nodes
#define NB (8 * NPAGE)         // sort buckets

typedef __attribute__((ext_vector_type(8))) __bf16 bf16x8;
typedef __attribute__((ext_vector_type(8))) _Float16 fp16x8;
typedef __attribute__((ext_vector_type(2))) _Float16 h2v;
typedef __attribute__((ext_vector_type(16))) float f32x16;

__device__ inline float u2f(unsigned u) { return __builtin_bit_cast(float, u); }
__device__ inline unsigned short f2b(float f) {
    __bf16 h = (__bf16)f;
    return __builtin_bit_cast(unsigned short, h);
}
__device__ inline unsigned short f2h(float f) {
    _Float16 h = (_Float16)f;
    return __builtin_bit_cast(unsigned short, h);
}
__device__ inline float blo(unsigned u) { return u2f(u << 16); }
__device__ inline float bhi(unsigned u) { return u2f(u & 0xffff0000u); }

// packed fp16: relu(a + b) on 2 lanes
__device__ inline unsigned hrelu2(unsigned a, unsigned b) {
    h2v x = __builtin_bit_cast(h2v, a);
    h2v y = __builtin_bit_cast(h2v, b);
    h2v s = x + y;
    h2v z = {(_Float16)0.f, (_Float16)0.f};
    h2v r = __builtin_elementwise_max(s, z);
    return __builtin_bit_cast(unsigned, r);
}

// ---------------- K2: d1,d2 = dist MLPs ----------------
__global__ void k_dmlp(const float* __restrict__ dmax,
                       const float* __restrict__ w1a, const float* __restrict__ b1a,
                       const float* __restrict__ w2a, const float* __restrict__ b2a,
                       const float* __restrict__ w1b, const float* __restrict__ b1b,
                       const float* __restrict__ w2b, const float* __restrict__ b2b,
                       float* __restrict__ d1, float* __restrict__ d2) {
    int i = blockIdx.x * 256 + threadIdx.x;
    if (i >= NN * KK) return;
    float dm = dmax[i];
    float a1 = 0.f, a2 = 0.f;
#pragma unroll 8
    for (int h = 0; h < HH; ++h) {
        float t1 = fmaxf(fmaf(dm, w1a[h], b1a[h]), 0.f);
        a1 = fmaf(t1, w2a[h], a1);
        float t2 = fmaxf(fmaf(dm, w1b[h], b1b[h]), 0.f);
        a2 = fmaf(t2, w2b[h], a2);
    }
    d1[i] = a1 + b2a[0];
    d2[i] = a2 + b2b[0];
}

// ---------------- x -> split fp16 (hi + lo*1024) ----------------
__global__ void k_x16(const float* __restrict__ x, unsigned short* __restrict__ xh,
                      unsigned short* __restrict__ xl) {
    int i = (blockIdx.x * 256 + threadIdx.x) * 8;
    if (i >= NN * IN_F) return;
    unsigned short vh[8], vl[8];
#pragma unroll
    for (int j = 0; j < 8; ++j) {
        float v = x[i + j];
        _Float16 hi = (_Float16)v;
        vh[j] = __builtin_bit_cast(unsigned short, hi);
        vl[j] = f2h((v - (float)hi) * 1024.f);
    }
    *(uint4*)(xh + i) = *(uint4*)vh;
    *(uint4*)(xl + i) = *(uint4*)vl;
}

// ---------------- K0: weight prep ----------------
// [0,256) bfuse | [256,16640) wt | [16640,82176) wt1 | [82176,114944) wt2 hi/lo
// | [114944,131328) wfuse hi/lo
__global__ void k_wprep(const float* __restrict__ w_pre, const float* __restrict__ b_pre,
                        const float* __restrict__ l1wh, const float* __restrict__ l1bh,
                        const float* __restrict__ ffw2, const float* __restrict__ ffw1,
                        const float* __restrict__ l2wh,
                        float* __restrict__ bfuse, unsigned short* __restrict__ wt,
                        unsigned short* __restrict__ wt1,
                        unsigned short* __restrict__ wt2h, unsigned short* __restrict__ wt2l,
                        unsigned short* __restrict__ wfh, unsigned short* __restrict__ wfl) {
    int gid = blockIdx.x * 256 + threadIdx.x;
    if (gid < 256) {
        int half = gid >> 7, h = gid & 127;
        const float* wh = l1wh + half * FEAT * HH + h;
        float acc = (half == 1) ? l1bh[h] : 0.f;
#pragma unroll
        for (int c = 0; c < FEAT; ++c) acc = fmaf(b_pre[c], wh[c * HH], acc);
        bfuse[gid] = acc;
    } else if (gid < 16640) {
        int i = gid - 256;
        int k = i >> 6, c = i & 63;
        wt[c * 256 + k] = f2h(ffw2[i]);
    } else if (gid < 82176) {
        int i = gid - 16640;
        int c = i >> 7, j = i & 127;
        float v = (c < 256) ? ffw1[j * 256 + c] : ffw1[(128 + j) * 256 + (c - 256)];
        wt1[c * 128 + j] = f2h(v);
    } else if (gid < 114944) {
        int i = gid - 82176;
        int c = i >> 7, j = i & 127;
        float v = (c < 128) ? l2wh[j * 128 + c] : l2wh[(128 + j) * 128 + (c - 128)];
        _Float16 hi = (_Float16)v;
        wt2h[c * 128 + j] = __builtin_bit_cast(unsigned short, hi);
        wt2l[c * 128 + j] = f2h((v - (float)hi) * 1024.f);
    } else if (gid < 131328) {
        int i = gid - 114944;
        int cc = i >> 6, j = i & 63;
        const float* wrow = w_pre + j * FEAT;
        float acc = 0.f;
#pragma unroll
        for (int c = 0; c < FEAT; ++c) {
            float wh = (cc < 128) ? l1wh[c * HH + cc] : l1wh[(FEAT + c) * HH + (cc - 128)];
            acc = fmaf(wrow[c], wh, acc);
        }
        _Float16 hi = (_Float16)acc;
        wfh[cc * 64 + j] = __builtin_bit_cast(unsigned short, hi);
        wfl[cc * 64 + j] = f2h((acc - (float)hi) * 1024.f);
    }
}

// ---------------- Edge sort ----------------
__global__ void k_hist(const int* __restrict__ ei, unsigned* __restrict__ hist) {
    int base = (blockIdx.x * 256 + threadIdx.x) * 8;
    if (base >= EE) return;
    int4 s0 = *(const int4*)(ei + base);
    int4 s1 = *(const int4*)(ei + base + 4);
    int4 d0 = *(const int4*)(ei + EE + base);
    int4 d1 = *(const int4*)(ei + EE + base + 4);
    int ss[8] = {s0.x, s0.y, s0.z, s0.w, s1.x, s1.y, s1.z, s1.w};
    int dd[8] = {d0.x, d0.y, d0.z, d0.w, d1.x, d1.y, d1.z, d1.w};
#pragma unroll
    for (int j = 0; j < 8; ++j) {
        int key = (ss[j] * 8 / NN) * NPAGE + (dd[j] >> 6);
        atomicAdd(&hist[key], 1u);
    }
}

__global__ __launch_bounds__(64) void k_scan(const unsigned* __restrict__ hist,
                                             unsigned* __restrict__ cursor) {
    int l = threadIdx.x;
    const int PER = 59;
    unsigned tot = 0;
    for (int j = 0; j < PER; ++j) {
        int i = l * PER + j;
        if (i < NB) tot += hist[i];
    }
    unsigned run = tot;
#pragma unroll
    for (int off = 1; off < 64; off <<= 1) {
        unsigned u = __shfl_up(run, off, 64);
        if (l >= off) run += u;
    }
    unsigned base = run - tot;
    for (int j = 0; j < PER; ++j) {
        int i = l * PER + j;
        if (i < NB) {
            cursor[i] = base;
            base += hist[i];
        }
    }
}

__global__ void k_scatter(const int* __restrict__ ei, unsigned* __restrict__ cursor,
                          uint4* __restrict__ sedge) {
    int base = (blockIdx.x * 256 + threadIdx.x) * 8;
    if (base >= EE) return;
    int4 s0 = *(const int4*)(ei + base);
    int4 s1 = *(const int4*)(ei + base + 4);
    int4 d0 = *(const int4*)(ei + EE + base);
    int4 d1 = *(const int4*)(ei + EE + base + 4);
    int ss[8] = {s0.x, s0.y, s0.z, s0.w, s1.x, s1.y, s1.z, s1.w};
    int dd[8] = {d0.x, d0.y, d0.z, d0.w, d1.x, d1.y, d1.z, d1.w};
    unsigned pp[8];
#pragma unroll
    for (int j = 0; j < 8; ++j) {
        int key = (ss[j] * 8 / NN) * NPAGE + (dd[j] >> 6);
        pp[j] = atomicAdd(&cursor[key], 1u);
    }
#pragma unroll
    for (int j = 0; j < 8; ++j)
        sedge[pp[j]] = make_uint4((unsigned)ss[j], (unsigned)dd[j], (unsigned)(base + j), 0u);
}

// ---------------- Unified node GEMM via split-fp16 MFMA (fp32-class accuracy) ----------------
// C = A @ Wt^T with A = Ah + Al/1024, W = Wh + Wl/1024 (fp16 pairs).
// D = Ah.Wh + (Ah.Wl + Al.Wh)/1024  (dropped term ~2.5e-7 rel).
template <int KD>
__global__ __launch_bounds__(256) void k_nodegemm(
    const unsigned short* __restrict__ Ah, const unsigned short* __restrict__ Al,
    const unsigned short* __restrict__ Wh, const unsigned short* __restrict__ Wl,
    const float* __restrict__ gbias, const float* __restrict__ sbias,
    unsigned short* __restrict__ Gb, float* __restrict__ S) {
    int t = threadIdx.x;
    int l = t & 63, w = t >> 6;
    int c = l & 31, kh = l >> 5;
    int nb = blockIdx.x * 32;
    int na = nb + c;
    if (na >= NN) na = NN - 1;
    fp16x8 afh[KD / 16], afl[KD / 16];
#pragma unroll
    for (int kt = 0; kt < KD / 16; ++kt) {
        afh[kt] = *(const fp16x8*)(Ah + na * KD + kt * 16 + kh * 8);
        afl[kt] = *(const fp16x8*)(Al + na * KD + kt * 16 + kh * 8);
    }
    f32x16 acch0, acch1, accl0, accl1;
#pragma unroll
    for (int i = 0; i < 16; ++i) { acch0[i] = 0.f; acch1[i] = 0.f; accl0[i] = 0.f; accl1[i] = 0.f; }
    int cb0 = w * 64, cb1 = w * 64 + 32;
#pragma unroll
    for (int kt = 0; kt < KD / 16; ++kt) {
        fp16x8 b0h = *(const fp16x8*)(Wh + (cb0 + c) * KD + kt * 16 + kh * 8);
        fp16x8 b0l = *(const fp16x8*)(Wl + (cb0 + c) * KD + kt * 16 + kh * 8);
        fp16x8 b1h = *(const fp16x8*)(Wh + (cb1 + c) * KD + kt * 16 + kh * 8);
        fp16x8 b1l = *(const fp16x8*)(Wl + (cb1 + c) * KD + kt * 16 + kh * 8);
        acch0 = __builtin_amdgcn_mfma_f32_32x32x16_f16(afh[kt], b0h, acch0, 0, 0, 0);
        accl0 = __builtin_amdgcn_mfma_f32_32x32x16_f16(afh[kt], b0l, accl0, 0, 0, 0);
        accl0 = __builtin_amdgcn_mfma_f32_32x32x16_f16(afl[kt], b0h, accl0, 0, 0, 0);
        acch1 = __builtin_amdgcn_mfma_f32_32x32x16_f16(afh[kt], b1h, acch1, 0, 0, 0);
        accl1 = __builtin_amdgcn_mfma_f32_32x32x16_f16(afh[kt], b1l, accl1, 0, 0, 0);
        accl1 = __builtin_amdgcn_mfma_f32_32x32x16_f16(afl[kt], b1h, accl1, 0, 0, 0);
    }
    const float inv1024 = 1.0f / 1024.0f;
#pragma unroll
    for (int half = 0; half < 2; ++half) {
        int col = (half ? cb1 : cb0) + c;
        bool isG = col < HH;
        float gb_ = (isG && gbias) ? gbias[col] : 0.f;
        float sb_ = (!isG) ? sbias[col - HH] : 0.f;
#pragma unroll
        for (int r = 0; r < 16; ++r) {
            int row = (r & 3) + 8 * (r >> 2) + 4 * kh;
            int n = nb + row;
            float v = half ? (acch1[r] + accl1[r] * inv1024)
                           : (acch0[r] + accl0[r] * inv1024);
            if (n < NN) {
                if (isG) Gb[n * HH + col] = f2b(v + gb_);
                else S[n * HH + (col - HH)] = v + sb_;
            }
        }
    }
}

// ---------------- K4: layer1 -> h1 split fp16 (hi + lo*1024) ----------------
__global__ void k_layer1(const unsigned* __restrict__ G1u, const float* __restrict__ S1,
                         const float* __restrict__ d1, const int* __restrict__ amax,
                         unsigned* __restrict__ hh, unsigned* __restrict__ hl) {
    int t = threadIdx.x;
    int n = blockIdx.x * 4 + (t >> 6);
    int l = t & 63;
    float2 sv = *(const float2*)(S1 + n * HH + 2 * l);
    float acc0 = 0.f, acc1 = 0.f;
    const int* arow = amax + n * KK;
    const float* drow = d1 + n * KK;
#pragma unroll
    for (int k = 0; k < KK; ++k) {
        int a = arow[k];
        float dk = drow[k];
        unsigned g = G1u[a * 64 + l];
        acc0 += fmaxf(fmaf(dk, blo(g), sv.x), 0.f);
        acc1 += fmaxf(fmaf(dk, bhi(g), sv.y), 0.f);
    }
    float a0 = acc0 * 0.04f, a1 = acc1 * 0.04f;
    _Float16 h0 = (_Float16)a0, h1v = (_Float16)a1;
    float r0 = (a0 - (float)h0) * 1024.f, r1 = (a1 - (float)h1v) * 1024.f;
    hh[n * 64 + l] = (unsigned)__builtin_bit_cast(unsigned short, h0) |
                     ((unsigned)__builtin_bit_cast(unsigned short, h1v) << 16);
    hl[n * 64 + l] = (unsigned)f2h(r0) | ((unsigned)f2h(r1) << 16);
}

// ---------------- K6: layer2 pos + norm + w_lin -> hl16 (fp16) ----------------
__global__ __launch_bounds__(256) void k_xpos2(
    const unsigned* __restrict__ G2u, const float* __restrict__ S2,
    const float* __restrict__ d2, const int* __restrict__ amax,
    const float* __restrict__ wp, const float* __restrict__ bp,
    const float* __restrict__ wlin, const float* __restrict__ blin,
    unsigned short* __restrict__ hl16) {
    __shared__ float xs[28];
    int t = threadIdx.x;
    int n = blockIdx.x;
    int w = t >> 6, l = t & 63;
    float2 sv = *(const float2*)(S2 + n * HH + 2 * l);
    float2 wpv = *(const float2*)(wp + 2 * l);
    float bpv = bp[0];
    const int* arow = amax + n * KK;
    const float* drow = d2 + n * KK;
    int kcnt = (w == 0) ? 7 : 6;
    unsigned gv[7];
    float dk[7];
#pragma unroll
    for (int j = 0; j < 7; ++j) {
        if (j < kcnt) {
            int k = w + 4 * j;
            int a = arow[k];
            gv[j] = G2u[a * 64 + l];
            dk[j] = drow[k];
        }
    }
    float v[7];
#pragma unroll
    for (int j = 0; j < 7; ++j) {
        if (j < kcnt) {
            v[j] = fmaxf(fmaf(dk[j], blo(gv[j]), sv.x), 0.f) * wpv.x +
                   fmaxf(fmaf(dk[j], bhi(gv[j]), sv.y), 0.f) * wpv.y;
        }
    }
#pragma unroll
    for (int s = 1; s < 64; s <<= 1) {
#pragma unroll
        for (int j = 0; j < 7; ++j) {
            if (j < kcnt) v[j] += __shfl_xor(v[j], s, 64);
        }
    }
    if (l == 0) {
#pragma unroll
        for (int j = 0; j < 7; ++j) {
            if (j < kcnt) xs[w + 4 * j] = v[j] + bpv;
        }
    }
    __syncthreads();
    if (t < HH) {
        float ss = 0.f;
#pragma unroll
        for (int k = 0; k < KK; ++k) { float x = xs[k]; ss = fmaf(x, x, ss); }
        float inv = 1.0f / fmaxf(sqrtf(ss), 1e-12f);
        float acc = blin[t];
#pragma unroll
        for (int k = 0; k < KK; ++k) {
            float x = fmaxf(xs[k], 0.f) * inv;
            acc = fmaf(x, wlin[k * HH + t], acc);
        }
        hl16[n * HH + t] = f2h(fmaxf(acc, 0.f));
    }
}

// ---------------- K7: ab = [hl@W1top | hl@W1bot + ff_b1] via MFMA (fp16 out) ----------------
__global__ __launch_bounds__(256) void k_ab_mfma(
    const unsigned short* __restrict__ hl16, const unsigned short* __restrict__ wt1,
    const float* __restrict__ ffb1, unsigned short* __restrict__ ab) {
    int t = threadIdx.x;
    int l = t & 63, w = t >> 6;
    int c = l & 31, kh = l >> 5;
    int nb = blockIdx.x * 32;
    int na = nb + c;
    if (na >= NN) na = NN - 1;
    fp16x8 af[8];
#pragma unroll
    for (int kt = 0; kt < 8; ++kt)
        af[kt] = *(const fp16x8*)(hl16 + na * 128 + kt * 16 + kh * 8);
    f32x16 acc[4];
#pragma unroll
    for (int g = 0; g < 4; ++g)
#pragma unroll
        for (int i = 0; i < 16; ++i) acc[g][i] = 0.f;
#pragma unroll
    for (int kt = 0; kt < 8; ++kt) {
#pragma unroll
        for (int g = 0; g < 4; ++g) {
            fp16x8 b = *(const fp16x8*)(wt1 + (w * 128 + g * 32 + c) * 128 + kt * 16 + kh * 8);
            acc[g] = __builtin_amdgcn_mfma_f32_32x32x16_f16(af[kt], b, acc[g], 0, 0, 0);
        }
    }
#pragma unroll
    for (int g = 0; g < 4; ++g) {
        int col = w * 128 + g * 32 + c;
        float bias = (col >= 256) ? ffb1[col - 256] : 0.f;
#pragma unroll
        for (int r = 0; r < 16; ++r) {
            int row = (r & 3) + 8 * (r >> 2) + 4 * kh;
            int n = nb + row;
            if (n < NN) ab[n * 512 + col] = f2h(acc[g][r] + bias);
        }
    }
}

// ---------------- K8: sorted edges, LDS-staged coalesced, fp16 MFMA ----------------
__global__ __launch_bounds__(256, 2) void k_edge_mfma(
    const unsigned short* __restrict__ abf, const uint4* __restrict__ sedge,
    const unsigned short* __restrict__ wt, const float* __restrict__ ffb2,
    float* __restrict__ out) {
    __shared__ uint4 P[128 * 32];  // 64 KB: 128 rows x 256 fp16, swizzled
    int t = threadIdx.x;
    int l = t & 63;
    int w = t >> 6;
    int c = l & 31, kh = l >> 5;

    fp16x8 wf0[16], wf1[16];
#pragma unroll
    for (int kt = 0; kt < 16; ++kt) {
        wf0[kt] = *(const fp16x8*)(wt + c * 256 + kt * 16 + kh * 8);
        wf1[kt] = *(const fp16x8*)(wt + (c + 32) * 256 + kt * 16 + kh * 8);
    }
    float bias0 = ffb2[c], bias1 = ffb2[c + 32];

    int xcd = blockIdx.x & 7;
    int slot = blockIdx.x >> 3;
    int seg = t & 31;
    int rb = t >> 5;

    for (int tl = slot; tl < NPAGE; tl += 64) {
        int tb = (xcd * NPAGE + tl) * 128;
#pragma unroll 4
        for (int r = 0; r < 16; ++r) {
            int row = r * 8 + rb;
            int pos = tb + row;
            uint4 rec = sedge[pos < EE ? pos : EE - 1];
            uint4 a = *(const uint4*)(abf + (size_t)rec.x * 512 + seg * 8);
            uint4 b = *(const uint4*)(abf + (size_t)rec.y * 512 + 256 + seg * 8);
            uint4 p;
            p.x = hrelu2(a.x, b.x);
            p.y = hrelu2(a.y, b.y);
            p.z = hrelu2(a.z, b.z);
            p.w = hrelu2(a.w, b.w);
            int col = (seg * 16) ^ ((row & 15) << 4);
            P[row * 32 + (col >> 4)] = p;
        }
        __syncthreads();
        f32x16 acc0, acc1;
#pragma unroll
        for (int i = 0; i < 16; ++i) { acc0[i] = 0.f; acc1[i] = 0.f; }
        int wrow = w * 32 + c;
        int sw = (wrow & 15) << 4;
#pragma unroll
        for (int kt = 0; kt < 16; ++kt) {
            int col = (kt * 32 + kh * 16) ^ sw;
            fp16x8 af = __builtin_bit_cast(fp16x8, P[wrow * 32 + (col >> 4)]);
            acc0 = __builtin_amdgcn_mfma_f32_32x32x16_f16(af, wf0[kt], acc0, 0, 0, 0);
            acc1 = __builtin_amdgcn_mfma_f32_32x32x16_f16(af, wf1[kt], acc1, 0, 0, 0);
        }
        int spos = tb + wrow;
        int eid = (int)sedge[spos < EE ? spos : EE - 1].z;
        int rbase = 4 * kh;
#pragma unroll
        for (int r = 0; r < 16; ++r) {
            int row = (r & 3) + 8 * (r >> 2) + rbase;
            int eidr = __shfl(eid, row, 64);
            if (tb + w * 32 + row < EE) {
                size_t o = (size_t)eidr * 64;
                out[o + c] = acc0[r] + bias0;
                out[o + 32 + c] = acc1[r] + bias1;
            }
        }
        __syncthreads();
    }
}

extern "C" void kernel_launch(void* const* d_in, const int* in_sizes, int n_in,
                              void* d_out, int out_size, void* d_ws, size_t ws_size,
                              hipStream_t stream) {
    const float* x     = (const float*)d_in[0];
    const float* dmax  = (const float*)d_in[1];
    const int*   amax  = (const int*)d_in[2];
    const int*   ei    = (const int*)d_in[3];
    const float* w_pre = (const float*)d_in[5];
    const float* b_pre = (const float*)d_in[6];
    const float* l1w1  = (const float*)d_in[7];
    const float* l1b1  = (const float*)d_in[8];
    const float* l1w2  = (const float*)d_in[9];
    const float* l1b2  = (const float*)d_in[10];
    const float* l1wh  = (const float*)d_in[11];
    const float* l1bh  = (const float*)d_in[12];
    const float* l2w1  = (const float*)d_in[15];
    const float* l2b1  = (const float*)d_in[16];
    const float* l2w2  = (const float*)d_in[17];
    const float* l2b2  = (const float*)d_in[18];
    const float* l2wh  = (const float*)d_in[19];
    const float* l2bh  = (const float*)d_in[20];
    const float* l2wp  = (const float*)d_in[21];
    const float* l2bp  = (const float*)d_in[22];
    const float* wlin  = (const float*)d_in[23];
    const float* blin  = (const float*)d_in[24];
    const float* ffw1  = (const float*)d_in[25];
    const float* ffb1  = (const float*)d_in[26];
    const float* ffw2  = (const float*)d_in[27];
    const float* ffb2  = (const float*)d_in[28];

    float* ws = (float*)d_ws;
    // Layout (float offsets):
    //   d1@0 (.75M)  d2@.75M (.75M)  Gb(ush)@1.5M (1.92M)  S@3.5M (3.84M)
    //   x_hi(ush)@7.5M (.96M)  x_lo@8.5M (.96M)
    //   h_hi@9.5M (1.92M)  h_lo@11.5M (1.92M)  hl16@13.5M (1.92M)
    //   sedge(uint4)@15.5M (1.92M)
    //   wfuse_hi@17.5M  wfuse_lo@17.51M  bfuse@17.52M  wt@17.53M  wt1@17.54M
    //   wt2_hi@17.58M  wt2_lo@17.60M  hist@17.62M  cursor@17.63M
    //   ab(ush)@0 (7.68M fl) — overlaps d1/d2/Gb/S/x_hi-prefix (all dead by k_ab_mfma)
    float* d1 = ws + 0;
    float* d2 = ws + 750000;
    unsigned short* Gb = (unsigned short*)(ws + 1500000);
    float* S  = ws + 3500000;
    unsigned short* xh = (unsigned short*)(ws + 7500000);
    unsigned short* xl = (unsigned short*)(ws + 8500000);
    unsigned* hhp = (unsigned*)(ws + 9500000);
    unsigned* hlp = (unsigned*)(ws + 11500000);
    unsigned short* hl16 = (unsigned short*)(ws + 13500000);
    uint4* sedge = (uint4*)(ws + 15500000);
    unsigned short* wfh = (unsigned short*)(ws + 17500000);
    unsigned short* wfl = (unsigned short*)(ws + 17510000);
    float* bfuse = ws + 17520000;
    unsigned short* wt = (unsigned short*)(ws + 17530000);
    unsigned short* wt1 = (unsigned short*)(ws + 17540000);
    unsigned short* wt2h = (unsigned short*)(ws + 17580000);
    unsigned short* wt2l = (unsigned short*)(ws + 17600000);
    unsigned* hist = (unsigned*)(ws + 17620000);
    unsigned* cursor = (unsigned*)(ws + 17630000);
    unsigned short* ab = (unsigned short*)ws;
    float* out = (float*)d_out;

    // Edge sort (independent; sedge region is private)
    hipMemsetAsync(hist, 0, NB * sizeof(unsigned), stream);
    k_hist<<<(EE / 8 + 255) / 256, 256, 0, stream>>>(ei, hist);
    k_scan<<<1, 64, 0, stream>>>(hist, cursor);
    k_scatter<<<(EE / 8 + 255) / 256, 256, 0, stream>>>(ei, cursor, sedge);

    // Node pipeline
    k_x16<<<938, 256, 0, stream>>>(x, xh, xl);
    k_dmlp<<<(NN * KK + 255) / 256, 256, 0, stream>>>(dmax, l1w1, l1b1, l1w2, l1b2,
                                                      l2w1, l2b1, l2w2, l2b2, d1, d2);
    k_wprep<<<513, 256, 0, stream>>>(w_pre, b_pre, l1wh, l1bh, ffw2, ffw1, l2wh,
                                     bfuse, wt, wt1, wt2h, wt2l, wfh, wfl);
    k_nodegemm<IN_F><<<938, 256, 0, stream>>>(xh, xl, wfh, wfl, bfuse, bfuse + 128, Gb, S);
    k_layer1<<<NN / 4, 256, 0, stream>>>((const unsigned*)Gb, S, d1, amax, hhp, hlp);
    k_nodegemm<HH><<<938, 256, 0, stream>>>((const unsigned short*)hhp,
                                            (const unsigned short*)hlp, wt2h, wt2l,
                                            nullptr, l2bh, Gb, S);
    k_xpos2<<<NN, 256, 0, stream>>>((const unsigned*)Gb, S, d2, amax, l2wp, l2bp,
                                    wlin, blin, hl16);
    k_ab_mfma<<<938, 256, 0, stream>>>(hl16, wt1, ffb1, ab);

    // Sorted, XCD-pinned, LDS-staged edge GEMM
    k_edge_mfma<<<512, 256, 0, stream>>>(ab, sedge, wt, ffb2, out);
}

// Round 10
// 359.176 us; speedup vs baseline: 1.2820x; 1.0022x over previous
//
#include <hip/hip_runtime.h>
#include <hip/hip_bf16.h>
#include <cmath>

#define NN 30000
#define KK 25
#define IN_F 64
#define FEAT 32
#define HH 128
#define OUTF 64
#define EE 480000
#define NPAGE 469              // dst pages of 64 nodes
#define NB (8 * NPAGE)         // sort buckets

typedef __attribute__((ext_vector_type(8))) __bf16 bf16x8;
typedef __attribute__((ext_vector_type(8))) _Float16 fp16x8;
typedef __attribute__((ext_vector_type(2))) _Float16 h2v;
typedef __attribute__((ext_vector_type(16))) float f32x16;

__device__ inline float u2f(unsigned u) { return __builtin_bit_cast(float, u); }
__device__ inline unsigned short f2b(float f) {
    __bf16 h = (__bf16)f;
    return __builtin_bit_cast(unsigned short, h);
}
__device__ inline unsigned short f2h(float f) {
    _Float16 h = (_Float16)f;
    return __builtin_bit_cast(unsigned short, h);
}
__device__ inline float blo(unsigned u) { return u2f(u << 16); }
__device__ inline float bhi(unsigned u) { return u2f(u & 0xffff0000u); }

// packed fp16: relu(a + b) on 2 lanes
__device__ inline unsigned hrelu2(unsigned a, unsigned b) {
    h2v x = __builtin_bit_cast(h2v, a);
    h2v y = __builtin_bit_cast(h2v, b);
    h2v s = x + y;
    h2v z = {(_Float16)0.f, (_Float16)0.f};
    h2v r = __builtin_elementwise_max(s, z);
    return __builtin_bit_cast(unsigned, r);
}

// ---------------- zero hist (replaces pathological hipMemsetAsync blit) ----------------
__global__ void k_zero(unsigned* __restrict__ p, int n) {
    int i = blockIdx.x * 256 + threadIdx.x;
    if (i < n) p[i] = 0u;
}

// ---------------- K2: d1,d2 = dist MLPs ----------------
__global__ void k_dmlp(const float* __restrict__ dmax,
                       const float* __restrict__ w1a, const float* __restrict__ b1a,
                       const float* __restrict__ w2a, const float* __restrict__ b2a,
                       const float* __restrict__ w1b, const float* __restrict__ b1b,
                       const float* __restrict__ w2b, const float* __restrict__ b2b,
                       float* __restrict__ d1, float* __restrict__ d2) {
    int i = blockIdx.x * 256 + threadIdx.x;
    if (i >= NN * KK) return;
    float dm = dmax[i];
    float a1 = 0.f, a2 = 0.f;
#pragma unroll 8
    for (int h = 0; h < HH; ++h) {
        float t1 = fmaxf(fmaf(dm, w1a[h], b1a[h]), 0.f);
        a1 = fmaf(t1, w2a[h], a1);
        float t2 = fmaxf(fmaf(dm, w1b[h], b1b[h]), 0.f);
        a2 = fmaf(t2, w2b[h], a2);
    }
    d1[i] = a1 + b2a[0];
    d2[i] = a2 + b2b[0];
}

// ---------------- x -> split fp16 (hi + lo*1024) ----------------
__global__ void k_x16(const float* __restrict__ x, unsigned short* __restrict__ xh,
                      unsigned short* __restrict__ xl) {
    int i = (blockIdx.x * 256 + threadIdx.x) * 8;
    if (i >= NN * IN_F) return;
    unsigned short vh[8], vl[8];
#pragma unroll
    for (int j = 0; j < 8; ++j) {
        float v = x[i + j];
        _Float16 hi = (_Float16)v;
        vh[j] = __builtin_bit_cast(unsigned short, hi);
        vl[j] = f2h((v - (float)hi) * 1024.f);
    }
    *(uint4*)(xh + i) = *(uint4*)vh;
    *(uint4*)(xl + i) = *(uint4*)vl;
}

// ---------------- K0: weight prep ----------------
// [0,256) bfuse | [256,16640) wt | [16640,82176) wt1 | [82176,114944) wt2 hi/lo
// | [114944,131328) wfuse hi/lo
__global__ void k_wprep(const float* __restrict__ w_pre, const float* __restrict__ b_pre,
                        const float* __restrict__ l1wh, const float* __restrict__ l1bh,
                        const float* __restrict__ ffw2, const float* __restrict__ ffw1,
                        const float* __restrict__ l2wh,
                        float* __restrict__ bfuse, unsigned short* __restrict__ wt,
                        unsigned short* __restrict__ wt1,
                        unsigned short* __restrict__ wt2h, unsigned short* __restrict__ wt2l,
                        unsigned short* __restrict__ wfh, unsigned short* __restrict__ wfl) {
    int gid = blockIdx.x * 256 + threadIdx.x;
    if (gid < 256) {
        int half = gid >> 7, h = gid & 127;
        const float* wh = l1wh + half * FEAT * HH + h;
        float acc = (half == 1) ? l1bh[h] : 0.f;
#pragma unroll
        for (int c = 0; c < FEAT; ++c) acc = fmaf(b_pre[c], wh[c * HH], acc);
        bfuse[gid] = acc;
    } else if (gid < 16640) {
        int i = gid - 256;
        int k = i >> 6, c = i & 63;
        wt[c * 256 + k] = f2h(ffw2[i]);
    } else if (gid < 82176) {
        int i = gid - 16640;
        int c = i >> 7, j = i & 127;
        float v = (c < 256) ? ffw1[j * 256 + c] : ffw1[(128 + j) * 256 + (c - 256)];
        wt1[c * 128 + j] = f2h(v);
    } else if (gid < 114944) {
        int i = gid - 82176;
        int c = i >> 7, j = i & 127;
        float v = (c < 128) ? l2wh[j * 128 + c] : l2wh[(128 + j) * 128 + (c - 128)];
        _Float16 hi = (_Float16)v;
        wt2h[c * 128 + j] = __builtin_bit_cast(unsigned short, hi);
        wt2l[c * 128 + j] = f2h((v - (float)hi) * 1024.f);
    } else if (gid < 131328) {
        int i = gid - 114944;
        int cc = i >> 6, j = i & 63;
        const float* wrow = w_pre + j * FEAT;
        float acc = 0.f;
#pragma unroll
        for (int c = 0; c < FEAT; ++c) {
            float wh = (cc < 128) ? l1wh[c * HH + cc] : l1wh[(FEAT + c) * HH + (cc - 128)];
            acc = fmaf(wrow[c], wh, acc);
        }
        _Float16 hi = (_Float16)acc;
        wfh[cc * 64 + j] = __builtin_bit_cast(unsigned short, hi);
        wfl[cc * 64 + j] = f2h((acc - (float)hi) * 1024.f);
    }
}

// ---------------- Edge sort ----------------
__global__ void k_hist(const int* __restrict__ ei, unsigned* __restrict__ hist) {
    int base = (blockIdx.x * 256 + threadIdx.x) * 8;
    if (base >= EE) return;
    int4 s0 = *(const int4*)(ei + base);
    int4 s1 = *(const int4*)(ei + base + 4);
    int4 d0 = *(const int4*)(ei + EE + base);
    int4 d1 = *(const int4*)(ei + EE + base + 4);
    int ss[8] = {s0.x, s0.y, s0.z, s0.w, s1.x, s1.y, s1.z, s1.w};
    int dd[8] = {d0.x, d0.y, d0.z, d0.w, d1.x, d1.y, d1.z, d1.w};
#pragma unroll
    for (int j = 0; j < 8; ++j) {
        int key = (ss[j] * 8 / NN) * NPAGE + (dd[j] >> 6);
        atomicAdd(&hist[key], 1u);
    }
}

__global__ __launch_bounds__(64) void k_scan(const unsigned* __restrict__ hist,
                                             unsigned* __restrict__ cursor) {
    int l = threadIdx.x;
    const int PER = 59;
    unsigned tot = 0;
    for (int j = 0; j < PER; ++j) {
        int i = l * PER + j;
        if (i < NB) tot += hist[i];
    }
    unsigned run = tot;
#pragma unroll
    for (int off = 1; off < 64; off <<= 1) {
        unsigned u = __shfl_up(run, off, 64);
        if (l >= off) run += u;
    }
    unsigned base = run - tot;
    for (int j = 0; j < PER; ++j) {
        int i = l * PER + j;
        if (i < NB) {
            cursor[i] = base;
            base += hist[i];
        }
    }
}

__global__ void k_scatter(const int* __restrict__ ei, unsigned* __restrict__ cursor,
                          uint4* __restrict__ sedge) {
    int base = (blockIdx.x * 256 + threadIdx.x) * 8;
    if (base >= EE) return;
    int4 s0 = *(const int4*)(ei + base);
    int4 s1 = *(const int4*)(ei + base + 4);
    int4 d0 = *(const int4*)(ei + EE + base);
    int4 d1 = *(const int4*)(ei + EE + base + 4);
    int ss[8] = {s0.x, s0.y, s0.z, s0.w, s1.x, s1.y, s1.z, s1.w};
    int dd[8] = {d0.x, d0.y, d0.z, d0.w, d1.x, d1.y, d1.z, d1.w};
    unsigned pp[8];
#pragma unroll
    for (int j = 0; j < 8; ++j) {
        int key = (ss[j] * 8 / NN) * NPAGE + (dd[j] >> 6);
        pp[j] = atomicAdd(&cursor[key], 1u);
    }
#pragma unroll
    for (int j = 0; j < 8; ++j)
        sedge[pp[j]] = make_uint4((unsigned)ss[j], (unsigned)dd[j], (unsigned)(base + j), 0u);
}

// ---------------- Unified node GEMM via split-fp16 MFMA (fp32-class accuracy) ----------------
// C = A @ Wt^T with A = Ah + Al/1024, W = Wh + Wl/1024 (fp16 pairs).
// D = Ah.Wh + (Ah.Wl + Al.Wh)/1024  (dropped term ~2.5e-7 rel).
template <int KD>
__global__ __launch_bounds__(256) void k_nodegemm(
    const unsigned short* __restrict__ Ah, const unsigned short* __restrict__ Al,
    const unsigned short* __restrict__ Wh, const unsigned short* __restrict__ Wl,
    const float* __restrict__ gbias, const float* __restrict__ sbias,
    unsigned short* __restrict__ Gb, float* __restrict__ S) {
    int t = threadIdx.x;
    int l = t & 63, w = t >> 6;
    int c = l & 31, kh = l >> 5;
    int nb = blockIdx.x * 32;
    int na = nb + c;
    if (na >= NN) na = NN - 1;
    fp16x8 afh[KD / 16], afl[KD / 16];
#pragma unroll
    for (int kt = 0; kt < KD / 16; ++kt) {
        afh[kt] = *(const fp16x8*)(Ah + na * KD + kt * 16 + kh * 8);
        afl[kt] = *(const fp16x8*)(Al + na * KD + kt * 16 + kh * 8);
    }
    f32x16 acch0, acch1, accl0, accl1;
#pragma unroll
    for (int i = 0; i < 16; ++i) { acch0[i] = 0.f; acch1[i] = 0.f; accl0[i] = 0.f; accl1[i] = 0.f; }
    int cb0 = w * 64, cb1 = w * 64 + 32;
#pragma unroll
    for (int kt = 0; kt < KD / 16; ++kt) {
        fp16x8 b0h = *(const fp16x8*)(Wh + (cb0 + c) * KD + kt * 16 + kh * 8);
        fp16x8 b0l = *(const fp16x8*)(Wl + (cb0 + c) * KD + kt * 16 + kh * 8);
        fp16x8 b1h = *(const fp16x8*)(Wh + (cb1 + c) * KD + kt * 16 + kh * 8);
        fp16x8 b1l = *(const fp16x8*)(Wl + (cb1 + c) * KD + kt * 16 + kh * 8);
        acch0 = __builtin_amdgcn_mfma_f32_32x32x16_f16(afh[kt], b0h, acch0, 0, 0, 0);
        accl0 = __builtin_amdgcn_mfma_f32_32x32x16_f16(afh[kt], b0l, accl0, 0, 0, 0);
        accl0 = __builtin_amdgcn_mfma_f32_32x32x16_f16(afl[kt], b0h, accl0, 0, 0, 0);
        acch1 = __builtin_amdgcn_mfma_f32_32x32x16_f16(afh[kt], b1h, acch1, 0, 0, 0);
        accl1 = __builtin_amdgcn_mfma_f32_32x32x16_f16(afh[kt], b1l, accl1, 0, 0, 0);
        accl1 = __builtin_amdgcn_mfma_f32_32x32x16_f16(afl[kt], b1h, accl1, 0, 0, 0);
    }
    const float inv1024 = 1.0f / 1024.0f;
#pragma unroll
    for (int half = 0; half < 2; ++half) {
        int col = (half ? cb1 : cb0) + c;
        bool isG = col < HH;
        float gb_ = (isG && gbias) ? gbias[col] : 0.f;
        float sb_ = (!isG) ? sbias[col - HH] : 0.f;
#pragma unroll
        for (int r = 0; r < 16; ++r) {
            int row = (r & 3) + 8 * (r >> 2) + 4 * kh;
            int n = nb + row;
            float v = half ? (acch1[r] + accl1[r] * inv1024)
                           : (acch0[r] + accl0[r] * inv1024);
            if (n < NN) {
                if (isG) Gb[n * HH + col] = f2b(v + gb_);
                else S[n * HH + (col - HH)] = v + sb_;
            }
        }
    }
}

// ---------------- K4: layer1 -> h1 split fp16 (hi + lo*1024) ----------------
__global__ void k_layer1(const unsigned* __restrict__ G1u, const float* __restrict__ S1,
                         const float* __restrict__ d1, const int* __restrict__ amax,
                         unsigned* __restrict__ hh, unsigned* __restrict__ hl) {
    int t = threadIdx.x;
    int n = blockIdx.x * 4 + (t >> 6);
    int l = t & 63;
    float2 sv = *(const float2*)(S1 + n * HH + 2 * l);
    float acc0 = 0.f, acc1 = 0.f;
    const int* arow = amax + n * KK;
    const float* drow = d1 + n * KK;
#pragma unroll
    for (int k = 0; k < KK; ++k) {
        int a = arow[k];
        float dk = drow[k];
        unsigned g = G1u[a * 64 + l];
        acc0 += fmaxf(fmaf(dk, blo(g), sv.x), 0.f);
        acc1 += fmaxf(fmaf(dk, bhi(g), sv.y), 0.f);
    }
    float a0 = acc0 * 0.04f, a1 = acc1 * 0.04f;
    _Float16 h0 = (_Float16)a0, h1v = (_Float16)a1;
    float r0 = (a0 - (float)h0) * 1024.f, r1 = (a1 - (float)h1v) * 1024.f;
    hh[n * 64 + l] = (unsigned)__builtin_bit_cast(unsigned short, h0) |
                     ((unsigned)__builtin_bit_cast(unsigned short, h1v) << 16);
    hl[n * 64 + l] = (unsigned)f2h(r0) | ((unsigned)f2h(r1) << 16);
}

// ---------------- K6: layer2 pos + norm + w_lin -> hl16 (fp16) ----------------
__global__ __launch_bounds__(256) void k_xpos2(
    const unsigned* __restrict__ G2u, const float* __restrict__ S2,
    const float* __restrict__ d2, const int* __restrict__ amax,
    const float* __restrict__ wp, const float* __restrict__ bp,
    const float* __restrict__ wlin, const float* __restrict__ blin,
    unsigned short* __restrict__ hl16) {
    __shared__ float xs[28];
    int t = threadIdx.x;
    int n = blockIdx.x;
    int w = t >> 6, l = t & 63;
    float2 sv = *(const float2*)(S2 + n * HH + 2 * l);
    float2 wpv = *(const float2*)(wp + 2 * l);
    float bpv = bp[0];
    const int* arow = amax + n * KK;
    const float* drow = d2 + n * KK;
    int kcnt = (w == 0) ? 7 : 6;
    unsigned gv[7];
    float dk[7];
#pragma unroll
    for (int j = 0; j < 7; ++j) {
        if (j < kcnt) {
            int k = w + 4 * j;
            int a = arow[k];
            gv[j] = G2u[a * 64 + l];
            dk[j] = drow[k];
        }
    }
    float v[7];
#pragma unroll
    for (int j = 0; j < 7; ++j) {
        if (j < kcnt) {
            v[j] = fmaxf(fmaf(dk[j], blo(gv[j]), sv.x), 0.f) * wpv.x +
                   fmaxf(fmaf(dk[j], bhi(gv[j]), sv.y), 0.f) * wpv.y;
        }
    }
#pragma unroll
    for (int s = 1; s < 64; s <<= 1) {
#pragma unroll
        for (int j = 0; j < 7; ++j) {
            if (j < kcnt) v[j] += __shfl_xor(v[j], s, 64);
        }
    }
    if (l == 0) {
#pragma unroll
        for (int j = 0; j < 7; ++j) {
            if (j < kcnt) xs[w + 4 * j] = v[j] + bpv;
        }
    }
    __syncthreads();
    if (t < HH) {
        float ss = 0.f;
#pragma unroll
        for (int k = 0; k < KK; ++k) { float x = xs[k]; ss = fmaf(x, x, ss); }
        float inv = 1.0f / fmaxf(sqrtf(ss), 1e-12f);
        float acc = blin[t];
#pragma unroll
        for (int k = 0; k < KK; ++k) {
            float x = fmaxf(xs[k], 0.f) * inv;
            acc = fmaf(x, wlin[k * HH + t], acc);
        }
        hl16[n * HH + t] = f2h(fmaxf(acc, 0.f));
    }
}

// ---------------- K7: ab = [hl@W1top | hl@W1bot + ff_b1] via MFMA (fp16 out) ----------------
__global__ __launch_bounds__(256) void k_ab_mfma(
    const unsigned short* __restrict__ hl16, const unsigned short* __restrict__ wt1,
    const float* __restrict__ ffb1, unsigned short* __restrict__ ab) {
    int t = threadIdx.x;
    int l = t & 63, w = t >> 6;
    int c = l & 31, kh = l >> 5;
    int nb = blockIdx.x * 32;
    int na = nb + c;
    if (na >= NN) na = NN - 1;
    fp16x8 af[8];
#pragma unroll
    for (int kt = 0; kt < 8; ++kt)
        af[kt] = *(const fp16x8*)(hl16 + na * 128 + kt * 16 + kh * 8);
    f32x16 acc[4];
#pragma unroll
    for (int g = 0; g < 4; ++g)
#pragma unroll
        for (int i = 0; i < 16; ++i) acc[g][i] = 0.f;
#pragma unroll
    for (int kt = 0; kt < 8; ++kt) {
#pragma unroll
        for (int g = 0; g < 4; ++g) {
            fp16x8 b = *(const fp16x8*)(wt1 + (w * 128 + g * 32 + c) * 128 + kt * 16 + kh * 8);
            acc[g] = __builtin_amdgcn_mfma_f32_32x32x16_f16(af[kt], b, acc[g], 0, 0, 0);
        }
    }
#pragma unroll
    for (int g = 0; g < 4; ++g) {
        int col = w * 128 + g * 32 + c;
        float bias = (col >= 256) ? ffb1[col - 256] : 0.f;
#pragma unroll
        for (int r = 0; r < 16; ++r) {
            int row = (r & 3) + 8 * (r >> 2) + 4 * kh;
            int n = nb + row;
            if (n < NN) ab[n * 512 + col] = f2h(acc[g][r] + bias);
        }
    }
}

// ---------------- K8: sorted edges, LDS-staged coalesced, fp16 MFMA ----------------
__global__ __launch_bounds__(256, 2) void k_edge_mfma(
    const unsigned short* __restrict__ abf, const uint4* __restrict__ sedge,
    const unsigned short* __restrict__ wt, const float* __restrict__ ffb2,
    float* __restrict__ out) {
    __shared__ uint4 P[128 * 32];  // 64 KB: 128 rows x 256 fp16, swizzled
    int t = threadIdx.x;
    int l = t & 63;
    int w = t >> 6;
    int c = l & 31, kh = l >> 5;

    fp16x8 wf0[16], wf1[16];
#pragma unroll
    for (int kt = 0; kt < 16; ++kt) {
        wf0[kt] = *(const fp16x8*)(wt + c * 256 + kt * 16 + kh * 8);
        wf1[kt] = *(const fp16x8*)(wt + (c + 32) * 256 + kt * 16 + kh * 8);
    }
    float bias0 = ffb2[c], bias1 = ffb2[c + 32];

    int xcd = blockIdx.x & 7;
    int slot = blockIdx.x >> 3;
    int seg = t & 31;
    int rb = t >> 5;

    for (int tl = slot; tl < NPAGE; tl += 64) {
        int tb = (xcd * NPAGE + tl) * 128;
#pragma unroll 4
        for (int r = 0; r < 16; ++r) {
            int row = r * 8 + rb;
            int pos = tb + row;
            uint4 rec = sedge[pos < EE ? pos : EE - 1];
            uint4 a = *(const uint4*)(abf + (size_t)rec.x * 512 + seg * 8);
            uint4 b = *(const uint4*)(abf + (size_t)rec.y * 512 + 256 + seg * 8);
            uint4 p;
            p.x = hrelu2(a.x, b.x);
            p.y = hrelu2(a.y, b.y);
            p.z = hrelu2(a.z, b.z);
            p.w = hrelu2(a.w, b.w);
            int col = (seg * 16) ^ ((row & 15) << 4);
            P[row * 32 + (col >> 4)] = p;
        }
        __syncthreads();
        f32x16 acc0, acc1;
#pragma unroll
        for (int i = 0; i < 16; ++i) { acc0[i] = 0.f; acc1[i] = 0.f; }
        int wrow = w * 32 + c;
        int sw = (wrow & 15) << 4;
#pragma unroll
        for (int kt = 0; kt < 16; ++kt) {
            int col = (kt * 32 + kh * 16) ^ sw;
            fp16x8 af = __builtin_bit_cast(fp16x8, P[wrow * 32 + (col >> 4)]);
            acc0 = __builtin_amdgcn_mfma_f32_32x32x16_f16(af, wf0[kt], acc0, 0, 0, 0);
            acc1 = __builtin_amdgcn_mfma_f32_32x32x16_f16(af, wf1[kt], acc1, 0, 0, 0);
        }
        int spos = tb + wrow;
        int eid = (int)sedge[spos < EE ? spos : EE - 1].z;
        int rbase = 4 * kh;
#pragma unroll
        for (int r = 0; r < 16; ++r) {
            int row = (r & 3) + 8 * (r >> 2) + rbase;
            int eidr = __shfl(eid, row, 64);
            if (tb + w * 32 + row < EE) {
                size_t o = (size_t)eidr * 64;
                out[o + c] = acc0[r] + bias0;
                out[o + 32 + c] = acc1[r] + bias1;
            }
        }
        __syncthreads();
    }
}

extern "C" void kernel_launch(void* const* d_in, const int* in_sizes, int n_in,
                              void* d_out, int out_size, void* d_ws, size_t ws_size,
                              hipStream_t stream) {
    const float* x     = (const float*)d_in[0];
    const float* dmax  = (const float*)d_in[1];
    const int*   amax  = (const int*)d_in[2];
    const int*   ei    = (const int*)d_in[3];
    const float* w_pre = (const float*)d_in[5];
    const float* b_pre = (const float*)d_in[6];
    const float* l1w1  = (const float*)d_in[7];
    const float* l1b1  = (const float*)d_in[8];
    const float* l1w2  = (const float*)d_in[9];
    const float* l1b2  = (const float*)d_in[10];
    const float* l1wh  = (const float*)d_in[11];
    const float* l1bh  = (const float*)d_in[12];
    const float* l2w1  = (const float*)d_in[15];
    const float* l2b1  = (const float*)d_in[16];
    const float* l2w2  = (const float*)d_in[17];
    const float* l2b2  = (const float*)d_in[18];
    const float* l2wh  = (const float*)d_in[19];
    const float* l2bh  = (const float*)d_in[20];
    const float* l2wp  = (const float*)d_in[21];
    const float* l2bp  = (const float*)d_in[22];
    const float* wlin  = (const float*)d_in[23];
    const float* blin  = (const float*)d_in[24];
    const float* ffw1  = (const float*)d_in[25];
    const float* ffb1  = (const float*)d_in[26];
    const float* ffw2  = (const float*)d_in[27];
    const float* ffb2  = (const float*)d_in[28];

    float* ws = (float*)d_ws;
    // Layout (float offsets):
    //   d1@0 (.75M)  d2@.75M (.75M)  Gb(ush)@1.5M (1.92M)  S@3.5M (3.84M)
    //   x_hi(ush)@7.5M (.96M)  x_lo@8.5M (.96M)
    //   h_hi@9.5M (1.92M)  h_lo@11.5M (1.92M)  hl16@13.5M (1.92M)
    //   sedge(uint4)@15.5M (1.92M)
    //   wfuse_hi@17.5M  wfuse_lo@17.51M  bfuse@17.52M  wt@17.53M  wt1@17.54M
    //   wt2_hi@17.58M  wt2_lo@17.60M  hist@17.62M  cursor@17.63M
    //   ab(ush)@0 (7.68M fl) — overlaps d1/d2/Gb/S/x_hi-prefix (all dead by k_ab_mfma)
    float* d1 = ws + 0;
    float* d2 = ws + 750000;
    unsigned short* Gb = (unsigned short*)(ws + 1500000);
    float* S  = ws + 3500000;
    unsigned short* xh = (unsigned short*)(ws + 7500000);
    unsigned short* xl = (unsigned short*)(ws + 8500000);
    unsigned* hhp = (unsigned*)(ws + 9500000);
    unsigned* hlp = (unsigned*)(ws + 11500000);
    unsigned short* hl16 = (unsigned short*)(ws + 13500000);
    uint4* sedge = (uint4*)(ws + 15500000);
    unsigned short* wfh = (unsigned short*)(ws + 17500000);
    unsigned short* wfl = (unsigned short*)(ws + 17510000);
    float* bfuse = ws + 17520000;
    unsigned short* wt = (unsigned short*)(ws + 17530000);
    unsigned short* wt1 = (unsigned short*)(ws + 17540000);
    unsigned short* wt2h = (unsigned short*)(ws + 17580000);
    unsigned short* wt2l = (unsigned short*)(ws + 17600000);
    unsigned* hist = (unsigned*)(ws + 17620000);
    unsigned* cursor = (unsigned*)(ws + 17630000);
    unsigned short* ab = (unsigned short*)ws;
    float* out = (float*)d_out;

    // Edge sort (independent; sedge region is private)
    k_zero<<<(NB + 255) / 256, 256, 0, stream>>>(hist, NB);
    k_hist<<<(EE / 8 + 255) / 256, 256, 0, stream>>>(ei, hist);
    k_scan<<<1, 64, 0, stream>>>(hist, cursor);
    k_scatter<<<(EE / 8 + 255) / 256, 256, 0, stream>>>(ei, cursor, sedge);

    // Node pipeline
    k_x16<<<938, 256, 0, stream>>>(x, xh, xl);
    k_dmlp<<<(NN * KK + 255) / 256, 256, 0, stream>>>(dmax, l1w1, l1b1, l1w2, l1b2,
                                                      l2w1, l2b1, l2w2, l2b2, d1, d2);
    k_wprep<<<513, 256, 0, stream>>>(w_pre, b_pre, l1wh, l1bh, ffw2, ffw1, l2wh,
                                     bfuse, wt, wt1, wt2h, wt2l, wfh, wfl);
    k_nodegemm<IN_F><<<938, 256, 0, stream>>>(xh, xl, wfh, wfl, bfuse, bfuse + 128, Gb, S);
    k_layer1<<<NN / 4, 256, 0, stream>>>((const unsigned*)Gb, S, d1, amax, hhp, hlp);
    k_nodegemm<HH><<<938, 256, 0, stream>>>((const unsigned short*)hhp,
                                            (const unsigned short*)hlp, wt2h, wt2l,
                                            nullptr, l2bh, Gb, S);
    k_xpos2<<<NN, 256, 0, stream>>>((const unsigned*)Gb, S, d2, amax, l2wp, l2bp,
                                    wlin, blin, hl16);
    k_ab_mfma<<<938, 256, 0, stream>>>(hl16, wt1, ffb1, ab);

    // Sorted, XCD-pinned, LDS-staged edge GEMM
    k_edge_mfma<<<512, 256, 0, stream>>>(ab, sedge, wt, ffb2, out);
}